// Round 2
// baseline (2586.382 us; speedup 1.0000x reference)
//
#include <hip/hip_runtime.h>

#define N_NODES 50000
#define N_EDGES 800000
#define IN_DIM  162
#define HID     256
#define KPAD1   192   // IN_DIM padded to multiple of 32

typedef __bf16 bf16;
typedef __bf16 bf16x8 __attribute__((ext_vector_type(8)));
typedef float  f32x4  __attribute__((ext_vector_type(4)));
typedef float  f32x8  __attribute__((ext_vector_type(8)));

// ---------------------------------------------------------------------------
// Transpose weight W[K][HID] (f32) -> Wt[HID][KPAD] (bf16), zero-pad k>=K.
__global__ void wt_transpose(const float* __restrict__ W, bf16* __restrict__ Wt,
                             int K, int KPAD)
{
    int idx = blockIdx.x * blockDim.x + threadIdx.x;
    int total = HID * KPAD;
    if (idx >= total) return;
    int n = idx / KPAD;
    int k = idx - n * KPAD;
    Wt[idx] = (k < K) ? (bf16)W[(size_t)k * HID + n] : (bf16)0.0f;
}

// ---------------------------------------------------------------------------
// feat (f32 [N, IN_DIM]) -> xsum (f32 [N, KPAD1], cols >= IN_DIM zeroed)
// fused column-sum of feat into colsum0 (must be pre-zeroed).
__global__ void feat_copy_colsum(const float* __restrict__ feat,
                                 float* __restrict__ xsum,
                                 float* __restrict__ colsum0)
{
    __shared__ float s[IN_DIM];
    int tid = threadIdx.x;
    if (tid < IN_DIM) s[tid] = 0.0f;
    __syncthreads();

    int idx = blockIdx.x * blockDim.x + tid;   // covers N*KPAD1 exactly
    int r = idx / KPAD1;
    int c = idx - r * KPAD1;
    float v = 0.0f;
    if (c < IN_DIM) {
        v = feat[(size_t)r * IN_DIM + c];
        atomicAdd(&s[c], v);
    }
    xsum[idx] = v;
    __syncthreads();
    if (tid < IN_DIM) atomicAdd(&colsum0[tid], s[tid]);
}

// ---------------------------------------------------------------------------
// Edge scatter: Y[dst[e], c] += (float)X[src[e], c].  One wave per edge.
template<int COLS, typename T>
__global__ void edge_scatter(const int* __restrict__ src,
                             const int* __restrict__ dst,
                             const T* __restrict__ X, int xstride,
                             float* __restrict__ Y, int ystride)
{
    int w    = threadIdx.x >> 6;
    int lane = threadIdx.x & 63;
    int e = blockIdx.x * 4 + w;
    if (e >= N_EDGES) return;
    int s = src[e];
    int d = dst[e];
    const T* xr = X + (size_t)s * xstride;
    float*   yr = Y + (size_t)d * ystride;
#pragma unroll
    for (int c0 = 0; c0 < COLS; c0 += 64) {
        int c = c0 + lane;
        if ((COLS & 63) == 0 || c < COLS)
            atomicAdd(&yr[c], (float)xr[c]);
    }
}

// ---------------------------------------------------------------------------
// GEMM: out = relu(X[M,KPAD] @ W[K,HID] + bias), via Wt[HID][KPAD] (bf16).
// Block = 256 threads (4 waves); block tile 64 rows x 256 cols; wave w owns
// rows [w*16, w*16+16) x all 256 cols = 16 MFMA tiles (16x16x32 bf16).
// A-frag: lane holds row (lane&15), k = (lane>>4)*8 + j   [m89/m120-verified]
// B-frag: lane holds col (lane&15), k = (lane>>4)*8 + j
// D:      lane holds col (lane&15), rows (lane>>4)*4 + r
template<int KPAD, bool XF32>
__launch_bounds__(256)
__global__ void gemm_relu(const void* __restrict__ Xv,
                          const bf16* __restrict__ Wt,      // [HID][KPAD] bf16
                          const float* __restrict__ bias,   // [HID] f32
                          bf16*  __restrict__ out_bf,       // nullable
                          float* __restrict__ out_f32,      // nullable
                          int M)
{
    const int tid  = threadIdx.x;
    const int w    = tid >> 6;
    const int lane = tid & 63;
    const int q    = lane >> 4;    // 0..3
    const int ln   = lane & 15;
    const int m_base = blockIdx.x * 64 + w * 16;

    int m = m_base + ln;           // A row this lane reads
    if (m >= M) m = M - 1;         // clamp (stores are guarded)

    f32x4 acc[16];
#pragma unroll
    for (int t = 0; t < 16; ++t)
#pragma unroll
        for (int r = 0; r < 4; ++r) acc[t][r] = 0.0f;

    const float* Xf = (const float*)Xv;
    const bf16*  Xb = (const bf16*)Xv;

    for (int k0 = 0; k0 < KPAD; k0 += 32) {
        bf16x8 a;
        if (XF32) {
            f32x8 af = *(const f32x8*)(Xf + (size_t)m * KPAD + k0 + q * 8);
#pragma unroll
            for (int j = 0; j < 8; ++j) a[j] = (bf16)af[j];
        } else {
            a = *(const bf16x8*)(Xb + (size_t)m * KPAD + k0 + q * 8);
        }
#pragma unroll
        for (int t = 0; t < 16; ++t) {
            bf16x8 b = *(const bf16x8*)(Wt + (size_t)(t * 16 + ln) * KPAD + k0 + q * 8);
            acc[t] = __builtin_amdgcn_mfma_f32_16x16x32_bf16(a, b, acc[t], 0, 0, 0);
        }
    }

    const int row0 = m_base + q * 4;
#pragma unroll
    for (int t = 0; t < 16; ++t) {
        const int c = t * 16 + ln;
        const float bv = bias[c];
#pragma unroll
        for (int r = 0; r < 4; ++r) {
            int mo = row0 + r;
            if (mo < M) {
                float v = acc[t][r] + bv;
                v = v > 0.0f ? v : 0.0f;
                if (out_bf)  out_bf[(size_t)mo * HID + c]  = (bf16)v;
                if (out_f32) out_f32[(size_t)mo * HID + c] = v;
            }
        }
    }
}

// ---------------------------------------------------------------------------
// Column sum of a [M, HID] matrix into out[HID] (pre-zeroed).
template<bool BF>
__global__ void colsum_kernel(const void* __restrict__ in, float* __restrict__ out,
                              int M, int rows_per_block)
{
    int c  = threadIdx.x;   // 256
    int r0 = blockIdx.x * rows_per_block;
    float acc = 0.0f;
    for (int i = 0; i < rows_per_block; ++i) {
        int r = r0 + i;
        if (r < M) {
            if (BF) acc += (float)((const bf16*)in)[(size_t)r * HID + c];
            else    acc += ((const float*)in)[(size_t)r * HID + c];
        }
    }
    atomicAdd(&out[c], acc);
}

// ---------------------------------------------------------------------------
// Graph head: three GEMVs + sum + final GEMV, single block of 256 threads.
// All weights f32 [K][HID], biases f32 [HID].
__global__ void graph_head(const float* __restrict__ cs0,
                           const float* __restrict__ cs1,
                           const float* __restrict__ cs2,
                           const float* __restrict__ g0w, const float* __restrict__ g0b,
                           const float* __restrict__ g1w, const float* __restrict__ g1b,
                           const float* __restrict__ g2w, const float* __restrict__ g2b,
                           const float* __restrict__ glw, const float* __restrict__ glb,
                           float* __restrict__ gvec)
{
    __shared__ float v0[IN_DIM], v1[HID], v2[HID], gs[HID];
    int t = threadIdx.x;
    if (t < IN_DIM) v0[t] = cs0[t];
    v1[t] = cs1[t];
    v2[t] = cs2[t];
    __syncthreads();

    float a0 = 0.0f, a1 = 0.0f, a2 = 0.0f;
    for (int k = 0; k < IN_DIM; ++k) a0 += v0[k] * g0w[k * HID + t];
    for (int k = 0; k < HID; ++k) {
        a1 += v1[k] * g1w[k * HID + t];
        a2 += v2[k] * g2w[k * HID + t];
    }
    float e0 = fmaxf(a0 + g0b[t], 0.0f);
    float e1 = fmaxf(a1 + g1b[t], 0.0f);
    float e2 = fmaxf(a2 + g2b[t], 0.0f);
    gs[t] = e0 + e1 + e2;
    __syncthreads();

    float a3 = 0.0f;
    for (int k = 0; k < HID; ++k) a3 += gs[k] * glw[k * HID + t];
    gvec[t] = fmaxf(a3 + glb[t], 0.0f);
}

// ---------------------------------------------------------------------------
// out[n,c] = node2[n,c] + gvec[c] (f32); 4 elements per thread.
__global__ void final_add(const float* __restrict__ node2,
                          const float* __restrict__ gvec,
                          float* __restrict__ out)
{
    int idx = blockIdx.x * blockDim.x + threadIdx.x;
    size_t base = (size_t)idx * 4;
    int c = (int)(base & (HID - 1));
    f32x4 v = *(const f32x4*)(node2 + base);
    f32x4 g = *(const f32x4*)(gvec + c);
    f32x4 o;
#pragma unroll
    for (int j = 0; j < 4; ++j) o[j] = v[j] + g[j];
    *(f32x4*)(out + base) = o;
}

// ---------------------------------------------------------------------------
extern "C" void kernel_launch(void* const* d_in, const int* in_sizes, int n_in,
                              void* d_out, int out_size, void* d_ws, size_t ws_size,
                              hipStream_t stream)
{
    const float* feat = (const float*)d_in[0];
    const int*   ei   = (const int*)d_in[1];
    const int*   src  = ei;
    const int*   dst  = ei + N_EDGES;
    const float* g0w = (const float*)d_in[2],  *g0b = (const float*)d_in[3];
    const float* g1w = (const float*)d_in[4],  *g1b = (const float*)d_in[5];
    const float* g2w = (const float*)d_in[6],  *g2b = (const float*)d_in[7];
    const float* glw = (const float*)d_in[8],  *glb = (const float*)d_in[9];
    const float* m1aw = (const float*)d_in[10], *m1ab = (const float*)d_in[11];
    const float* m1bw = (const float*)d_in[12], *m1bb = (const float*)d_in[13];
    const float* m2aw = (const float*)d_in[14], *m2ab = (const float*)d_in[15];
    const float* m2bw = (const float*)d_in[16], *m2bb = (const float*)d_in[17];
    float* out = (float*)d_out;

    char* ws = (char*)d_ws;
    size_t off = 0;
    auto alloc = [&](size_t bytes) -> void* {
        void* p = ws + off;
        off += (bytes + 255) & ~(size_t)255;
        return p;
    };
    float* xsum  = (float*)alloc((size_t)N_NODES * KPAD1 * 4); // feat + agg1
    float* y2    = (float*)alloc((size_t)N_NODES * HID * 4);   // node1 + agg2
    float* node2 = (float*)alloc((size_t)N_NODES * HID * 4);
    bf16*  h1    = (bf16*) alloc((size_t)N_NODES * HID * 2);   // reused as h2
    bf16*  node1 = (bf16*) alloc((size_t)N_NODES * HID * 2);
    bf16*  Wt1   = (bf16*) alloc((size_t)HID * KPAD1 * 2);
    bf16*  Wt2   = (bf16*) alloc((size_t)HID * HID * 2);
    bf16*  Wt3   = (bf16*) alloc((size_t)HID * HID * 2);
    bf16*  Wt4   = (bf16*) alloc((size_t)HID * HID * 2);
    float* csums = (float*)alloc((192 + 256 + 256 + 256) * 4);
    float* colsum0 = csums;            // 192 (162 used)
    float* colsum1 = csums + 192;      // 256
    float* colsum2 = csums + 448;      // 256
    float* gvec    = csums + 704;      // 256

    hipMemsetAsync(csums, 0, 704 * 4, stream);

    // weight transposes (tiny)
    wt_transpose<<<(HID * KPAD1 + 255) / 256, 256, 0, stream>>>(m1aw, Wt1, IN_DIM, KPAD1);
    wt_transpose<<<(HID * HID + 255) / 256, 256, 0, stream>>>(m1bw, Wt2, HID, HID);
    wt_transpose<<<(HID * HID + 255) / 256, 256, 0, stream>>>(m2aw, Wt3, HID, HID);
    wt_transpose<<<(HID * HID + 255) / 256, 256, 0, stream>>>(m2bw, Wt4, HID, HID);

    // xsum = feat (padded), colsum0 = sum(feat, axis=0)
    feat_copy_colsum<<<(N_NODES * KPAD1) / 256, 256, 0, stream>>>(feat, xsum, colsum0);

    // xsum[dst] += feat[src]
    edge_scatter<IN_DIM, float><<<(N_EDGES + 3) / 4, 256, 0, stream>>>(src, dst, feat, IN_DIM, xsum, KPAD1);

    const int gblocks = (N_NODES + 63) / 64;
    // h1 = relu(xsum @ m1a_w + b)
    gemm_relu<KPAD1, true><<<gblocks, 256, 0, stream>>>(xsum, Wt1, m1ab, h1, nullptr, N_NODES);
    // node1 = relu(h1 @ m1b_w + b); also y2 = node1 (f32)
    gemm_relu<HID, false><<<gblocks, 256, 0, stream>>>(h1, Wt2, m1bb, node1, y2, N_NODES);
    // colsum1 = sum(node1, axis=0)
    colsum_kernel<true><<<250, 256, 0, stream>>>(node1, colsum1, N_NODES, 200);
    // y2[dst] += node1[src]
    edge_scatter<HID, bf16><<<(N_EDGES + 3) / 4, 256, 0, stream>>>(src, dst, node1, HID, y2, HID);
    // h2 = relu(y2 @ m2a_w + b)  (reuse h1 buffer)
    gemm_relu<HID, true><<<gblocks, 256, 0, stream>>>(y2, Wt3, m2ab, h1, nullptr, N_NODES);
    // node2 = relu(h2 @ m2b_w + b) (f32)
    gemm_relu<HID, false><<<gblocks, 256, 0, stream>>>(h1, Wt4, m2bb, nullptr, node2, N_NODES);
    // colsum2 = sum(node2, axis=0)
    colsum_kernel<false><<<250, 256, 0, stream>>>(node2, colsum2, N_NODES, 200);
    // graph head -> gvec = g_last
    graph_head<<<1, 256, 0, stream>>>(colsum0, colsum1, colsum2,
                                      g0w, g0b, g1w, g1b, g2w, g2b, glw, glb, gvec);
    // out = node2 + gvec
    final_add<<<((size_t)N_NODES * HID / 4 + 255) / 256, 256, 0, stream>>>(node2, gvec, out);
    (void)in_sizes; (void)n_in; (void)out_size; (void)ws_size;
}

// Round 3
// 1038.616 us; speedup vs baseline: 2.4902x; 2.4902x over previous
//
#include <hip/hip_runtime.h>

#define N_NODES 50000
#define N_EDGES 800000
#define IN_DIM  162
#define HID     256
#define KPAD1   192   // IN_DIM padded to multiple of 32

typedef __bf16 bf16;
typedef __bf16 bf16x8 __attribute__((ext_vector_type(8)));
typedef __bf16 bf16x4 __attribute__((ext_vector_type(4)));
typedef float  f32x4  __attribute__((ext_vector_type(4)));

// ---------------------------------------------------------------------------
// Transpose weight W[K][HID] (f32) -> Wt[HID][KPAD] (bf16), zero-pad k>=K.
__global__ void wt_transpose(const float* __restrict__ W, bf16* __restrict__ Wt,
                             int K, int KPAD)
{
    int idx = blockIdx.x * blockDim.x + threadIdx.x;
    int total = HID * KPAD;
    if (idx >= total) return;
    int n = idx / KPAD;
    int k = idx - n * KPAD;
    Wt[idx] = (k < K) ? (bf16)W[(size_t)k * HID + n] : (bf16)0.0f;
}

// ---------------------------------------------------------------------------
// CSR build, step 1: degree histogram over dst.
__global__ void degree_hist(const int* __restrict__ dst, int* __restrict__ deg)
{
    int e = blockIdx.x * blockDim.x + threadIdx.x;   // grid covers N_EDGES exactly
    atomicAdd(&deg[dst[e]], 1);
}

// CSR build, step 2: exclusive scan of deg -> rowptr[0..N], cursor copy.
// Single block, 1024 threads, chunked + Hillis-Steele on chunk sums.
__global__ void scan_rowptr(const int* __restrict__ deg,
                            int* __restrict__ rowptr, int* __restrict__ cursor)
{
    const int T = 1024;
    __shared__ int part[T];
    int t = threadIdx.x;
    const int CH = (N_NODES + T - 1) / T;   // 49
    int base = t * CH;
    int s = 0;
    for (int i = 0; i < CH; ++i) {
        int idx = base + i;
        if (idx < N_NODES) s += deg[idx];
    }
    part[t] = s;
    __syncthreads();
    for (int off = 1; off < T; off <<= 1) {
        int v = (t >= off) ? part[t - off] : 0;
        __syncthreads();
        part[t] += v;
        __syncthreads();
    }
    int run = part[t] - s;    // exclusive prefix of this chunk
    for (int i = 0; i < CH; ++i) {
        int idx = base + i;
        if (idx < N_NODES) {
            rowptr[idx] = run;
            cursor[idx] = run;
            run += deg[idx];
        }
    }
    if (t == T - 1) rowptr[N_NODES] = part[T - 1];
}

// CSR build, step 3: fill src ids grouped by dst.
__global__ void csr_fill(const int* __restrict__ src, const int* __restrict__ dst,
                         int* __restrict__ cursor, int* __restrict__ csr_src)
{
    int e = blockIdx.x * blockDim.x + threadIdx.x;
    int p = atomicAdd(&cursor[dst[e]], 1);
    csr_src[p] = src[e];
}

// ---------------------------------------------------------------------------
// colsum0[c] = sum_n feat[n][c]; 250 blocks x 192 threads, 200 rows/block.
__global__ void colsum_feat(const float* __restrict__ feat, float* __restrict__ colsum0)
{
    int c  = threadIdx.x;          // 0..191, only <162 active
    int r0 = blockIdx.x * 200;
    if (c >= IN_DIM) return;
    float acc = 0.0f;
    for (int i = 0; i < 200; ++i) {
        int r = r0 + i;
        if (r < N_NODES) acc += feat[(size_t)r * IN_DIM + c];
    }
    atomicAdd(&colsum0[c], acc);
}

// ---------------------------------------------------------------------------
// Gather layer 1: xsum[n][c] = bf16( feat[n][c] + sum_{s in in(n)} feat[s][c] )
// One wave per node; 192 padded cols = 3 chunks of 64 (cols >= 162 stay 0).
__global__ void gather1(const float* __restrict__ feat,
                        const int* __restrict__ rowptr,
                        const int* __restrict__ csr_src,
                        bf16* __restrict__ xsum)
{
    int wave = threadIdx.x >> 6;
    int lane = threadIdx.x & 63;
    int n = blockIdx.x * 4 + wave;
    if (n >= N_NODES) return;

    const int c0 = lane, c1 = 64 + lane, c2 = 128 + lane;
    const bool v2 = (c2 < IN_DIM);
    const float* fr = feat + (size_t)n * IN_DIM;
    float a0 = fr[c0];
    float a1 = fr[c1];
    float a2 = v2 ? fr[c2] : 0.0f;

    int jb = rowptr[n], je = rowptr[n + 1];
    for (; jb + 1 < je; jb += 2) {
        int s0 = csr_src[jb], s1 = csr_src[jb + 1];
        const float* r0 = feat + (size_t)s0 * IN_DIM;
        const float* r1 = feat + (size_t)s1 * IN_DIM;
        a0 += r0[c0] + r1[c0];
        a1 += r0[c1] + r1[c1];
        if (v2) a2 += r0[c2] + r1[c2];
    }
    if (jb < je) {
        const float* r0 = feat + (size_t)csr_src[jb] * IN_DIM;
        a0 += r0[c0];
        a1 += r0[c1];
        if (v2) a2 += r0[c2];
    }
    bf16* xr = xsum + (size_t)n * KPAD1;
    xr[c0] = (bf16)a0;
    xr[c1] = (bf16)a1;
    xr[c2] = v2 ? (bf16)a2 : (bf16)0.0f;
}

// ---------------------------------------------------------------------------
// Gather layer 2: y2[n][0..255] = bf16( node1[n][:] + sum node1[src][:] )
// One wave per node; lane owns 4 consecutive cols (bf16x4 = 8B/lane).
__global__ void gather2(const bf16* __restrict__ node1,
                        const int* __restrict__ rowptr,
                        const int* __restrict__ csr_src,
                        bf16* __restrict__ y2)
{
    int wave = threadIdx.x >> 6;
    int lane = threadIdx.x & 63;
    int n = blockIdx.x * 4 + wave;
    if (n >= N_NODES) return;

    const int c = lane * 4;
    f32x4 acc;
    bf16x4 t0 = *(const bf16x4*)(node1 + (size_t)n * HID + c);
#pragma unroll
    for (int j = 0; j < 4; ++j) acc[j] = (float)t0[j];

    int jb = rowptr[n], je = rowptr[n + 1];
    for (; jb + 1 < je; jb += 2) {
        int s0 = csr_src[jb], s1 = csr_src[jb + 1];
        bf16x4 u0 = *(const bf16x4*)(node1 + (size_t)s0 * HID + c);
        bf16x4 u1 = *(const bf16x4*)(node1 + (size_t)s1 * HID + c);
#pragma unroll
        for (int j = 0; j < 4; ++j) acc[j] += (float)u0[j] + (float)u1[j];
    }
    if (jb < je) {
        bf16x4 u0 = *(const bf16x4*)(node1 + (size_t)csr_src[jb] * HID + c);
#pragma unroll
        for (int j = 0; j < 4; ++j) acc[j] += (float)u0[j];
    }
    bf16x4 o;
#pragma unroll
    for (int j = 0; j < 4; ++j) o[j] = (bf16)acc[j];
    *(bf16x4*)(y2 + (size_t)n * HID + c) = o;
}

// ---------------------------------------------------------------------------
// GEMM: out = relu(X[M,KPAD](bf16) @ W + bias) via Wt[HID][KPAD] (bf16).
// Block = 4 waves; tile 64 rows x 256 cols; wave owns 16 rows x 256 cols.
// A-frag: lane holds row (lane&15), k = (lane>>4)*8 + j   [m89-verified]
// B-frag: lane holds col (lane&15), k = (lane>>4)*8 + j
// D:      lane holds col (lane&15), rows (lane>>4)*4 + r
template<int KPAD>
__launch_bounds__(256)
__global__ void gemm_relu(const bf16* __restrict__ X,
                          const bf16* __restrict__ Wt,      // [HID][KPAD]
                          const float* __restrict__ bias,   // [HID]
                          bf16*  __restrict__ out_bf,       // nullable
                          float* __restrict__ out_f32,      // nullable
                          int M)
{
    const int tid  = threadIdx.x;
    const int w    = tid >> 6;
    const int lane = tid & 63;
    const int q    = lane >> 4;
    const int ln   = lane & 15;
    const int m_base = blockIdx.x * 64 + w * 16;

    int m = m_base + ln;
    if (m >= M) m = M - 1;   // clamp (stores guarded)

    f32x4 acc[16];
#pragma unroll
    for (int t = 0; t < 16; ++t)
#pragma unroll
        for (int r = 0; r < 4; ++r) acc[t][r] = 0.0f;

    for (int k0 = 0; k0 < KPAD; k0 += 32) {
        bf16x8 a = *(const bf16x8*)(X + (size_t)m * KPAD + k0 + q * 8);
#pragma unroll
        for (int t = 0; t < 16; ++t) {
            bf16x8 b = *(const bf16x8*)(Wt + (size_t)(t * 16 + ln) * KPAD + k0 + q * 8);
            acc[t] = __builtin_amdgcn_mfma_f32_16x16x32_bf16(a, b, acc[t], 0, 0, 0);
        }
    }

    const int row0 = m_base + q * 4;
#pragma unroll
    for (int t = 0; t < 16; ++t) {
        const int c = t * 16 + ln;
        const float bv = bias[c];
#pragma unroll
        for (int r = 0; r < 4; ++r) {
            int mo = row0 + r;
            if (mo < M) {
                float v = acc[t][r] + bv;
                v = v > 0.0f ? v : 0.0f;
                if (out_bf)  out_bf[(size_t)mo * HID + c]  = (bf16)v;
                if (out_f32) out_f32[(size_t)mo * HID + c] = v;
            }
        }
    }
}

// ---------------------------------------------------------------------------
// Column sum of a [M, HID] matrix into out[HID] (pre-zeroed).
template<bool BF>
__global__ void colsum_kernel(const void* __restrict__ in, float* __restrict__ out,
                              int M, int rows_per_block)
{
    int c  = threadIdx.x;   // 256
    int r0 = blockIdx.x * rows_per_block;
    float acc = 0.0f;
    for (int i = 0; i < rows_per_block; ++i) {
        int r = r0 + i;
        if (r < M) {
            if (BF) acc += (float)((const bf16*)in)[(size_t)r * HID + c];
            else    acc += ((const float*)in)[(size_t)r * HID + c];
        }
    }
    atomicAdd(&out[c], acc);
}

// ---------------------------------------------------------------------------
// Graph head: three GEMVs + sum + final GEMV, single block of 256 threads.
__global__ void graph_head(const float* __restrict__ cs0,
                           const float* __restrict__ cs1,
                           const float* __restrict__ cs2,
                           const float* __restrict__ g0w, const float* __restrict__ g0b,
                           const float* __restrict__ g1w, const float* __restrict__ g1b,
                           const float* __restrict__ g2w, const float* __restrict__ g2b,
                           const float* __restrict__ glw, const float* __restrict__ glb,
                           float* __restrict__ gvec)
{
    __shared__ float v0[IN_DIM], v1[HID], v2[HID], gs[HID];
    int t = threadIdx.x;
    if (t < IN_DIM) v0[t] = cs0[t];
    v1[t] = cs1[t];
    v2[t] = cs2[t];
    __syncthreads();

    float a0 = 0.0f, a1 = 0.0f, a2 = 0.0f;
    for (int k = 0; k < IN_DIM; ++k) a0 += v0[k] * g0w[k * HID + t];
    for (int k = 0; k < HID; ++k) {
        a1 += v1[k] * g1w[k * HID + t];
        a2 += v2[k] * g2w[k * HID + t];
    }
    float e0 = fmaxf(a0 + g0b[t], 0.0f);
    float e1 = fmaxf(a1 + g1b[t], 0.0f);
    float e2 = fmaxf(a2 + g2b[t], 0.0f);
    gs[t] = e0 + e1 + e2;
    __syncthreads();

    float a3 = 0.0f;
    for (int k = 0; k < HID; ++k) a3 += gs[k] * glw[k * HID + t];
    gvec[t] = fmaxf(a3 + glb[t], 0.0f);
}

// ---------------------------------------------------------------------------
// out[n,c] = node2[n,c] + gvec[c] (f32); 4 elements per thread.
__global__ void final_add(const float* __restrict__ node2,
                          const float* __restrict__ gvec,
                          float* __restrict__ out)
{
    int idx = blockIdx.x * blockDim.x + threadIdx.x;
    size_t base = (size_t)idx * 4;
    int c = (int)(base & (HID - 1));
    f32x4 v = *(const f32x4*)(node2 + base);
    f32x4 g = *(const f32x4*)(gvec + c);
    f32x4 o;
#pragma unroll
    for (int j = 0; j < 4; ++j) o[j] = v[j] + g[j];
    *(f32x4*)(out + base) = o;
}

// ---------------------------------------------------------------------------
extern "C" void kernel_launch(void* const* d_in, const int* in_sizes, int n_in,
                              void* d_out, int out_size, void* d_ws, size_t ws_size,
                              hipStream_t stream)
{
    const float* feat = (const float*)d_in[0];
    const int*   ei   = (const int*)d_in[1];
    const int*   src  = ei;
    const int*   dst  = ei + N_EDGES;
    const float* g0w = (const float*)d_in[2],  *g0b = (const float*)d_in[3];
    const float* g1w = (const float*)d_in[4],  *g1b = (const float*)d_in[5];
    const float* g2w = (const float*)d_in[6],  *g2b = (const float*)d_in[7];
    const float* glw = (const float*)d_in[8],  *glb = (const float*)d_in[9];
    const float* m1aw = (const float*)d_in[10], *m1ab = (const float*)d_in[11];
    const float* m1bw = (const float*)d_in[12], *m1bb = (const float*)d_in[13];
    const float* m2aw = (const float*)d_in[14], *m2ab = (const float*)d_in[15];
    const float* m2bw = (const float*)d_in[16], *m2bb = (const float*)d_in[17];
    float* out = (float*)d_out;

    char* ws = (char*)d_ws;
    size_t off = 0;
    auto alloc = [&](size_t bytes) -> void* {
        void* p = ws + off;
        off += (bytes + 255) & ~(size_t)255;
        return p;
    };
    bf16*  xsum  = (bf16*) alloc((size_t)N_NODES * KPAD1 * 2); // bf16(x+agg1)
    bf16*  y2    = (bf16*) alloc((size_t)N_NODES * HID * 2);   // bf16(node1+agg2)
    float* node2 = (float*)alloc((size_t)N_NODES * HID * 4);
    bf16*  h1    = (bf16*) alloc((size_t)N_NODES * HID * 2);   // reused as h2
    bf16*  node1 = (bf16*) alloc((size_t)N_NODES * HID * 2);
    bf16*  Wt1   = (bf16*) alloc((size_t)HID * KPAD1 * 2);
    bf16*  Wt2   = (bf16*) alloc((size_t)HID * HID * 2);
    bf16*  Wt3   = (bf16*) alloc((size_t)HID * HID * 2);
    bf16*  Wt4   = (bf16*) alloc((size_t)HID * HID * 2);
    int*   deg     = (int*)alloc((size_t)N_NODES * 4);
    int*   rowptr  = (int*)alloc((size_t)(N_NODES + 1) * 4);
    int*   cursor  = (int*)alloc((size_t)N_NODES * 4);
    int*   csr_src = (int*)alloc((size_t)N_EDGES * 4);
    float* csums = (float*)alloc((192 + 256 + 256 + 256) * 4);
    float* colsum0 = csums;            // 192 (162 used)
    float* colsum1 = csums + 192;      // 256
    float* colsum2 = csums + 448;      // 256
    float* gvec    = csums + 704;      // 256

    hipMemsetAsync(csums, 0, 704 * 4, stream);
    hipMemsetAsync(deg, 0, (size_t)N_NODES * 4, stream);

    // weight transposes (tiny)
    wt_transpose<<<(HID * KPAD1 + 255) / 256, 256, 0, stream>>>(m1aw, Wt1, IN_DIM, KPAD1);
    wt_transpose<<<(HID * HID + 255) / 256, 256, 0, stream>>>(m1bw, Wt2, HID, HID);
    wt_transpose<<<(HID * HID + 255) / 256, 256, 0, stream>>>(m2aw, Wt3, HID, HID);
    wt_transpose<<<(HID * HID + 255) / 256, 256, 0, stream>>>(m2bw, Wt4, HID, HID);

    // CSR build (grouped by dst)
    degree_hist<<<N_EDGES / 256, 256, 0, stream>>>(dst, deg);
    scan_rowptr<<<1, 1024, 0, stream>>>(deg, rowptr, cursor);
    csr_fill<<<N_EDGES / 256, 256, 0, stream>>>(src, dst, cursor, csr_src);

    // colsum0 = sum(feat, axis=0)
    colsum_feat<<<250, 192, 0, stream>>>(feat, colsum0);

    // xsum = bf16(feat + gather(feat))
    gather1<<<(N_NODES + 3) / 4, 256, 0, stream>>>(feat, rowptr, csr_src, xsum);

    const int gblocks = (N_NODES + 63) / 64;
    // h1 = relu(xsum @ m1a_w + b)
    gemm_relu<KPAD1><<<gblocks, 256, 0, stream>>>(xsum, Wt1, m1ab, h1, nullptr, N_NODES);
    // node1 = relu(h1 @ m1b_w + b)
    gemm_relu<HID><<<gblocks, 256, 0, stream>>>(h1, Wt2, m1bb, node1, nullptr, N_NODES);
    // colsum1 = sum(node1, axis=0)
    colsum_kernel<true><<<250, 256, 0, stream>>>(node1, colsum1, N_NODES, 200);
    // y2 = bf16(node1 + gather(node1))
    gather2<<<(N_NODES + 3) / 4, 256, 0, stream>>>(node1, rowptr, csr_src, y2);
    // h2 = relu(y2 @ m2a_w + b)  (reuse h1 buffer)
    gemm_relu<HID><<<gblocks, 256, 0, stream>>>(y2, Wt3, m2ab, h1, nullptr, N_NODES);
    // node2 = relu(h2 @ m2b_w + b) (f32)
    gemm_relu<HID><<<gblocks, 256, 0, stream>>>(h1, Wt4, m2bb, nullptr, node2, N_NODES);
    // colsum2 = sum(node2, axis=0)
    colsum_kernel<false><<<250, 256, 0, stream>>>(node2, colsum2, N_NODES, 200);
    // graph head -> gvec = g_last
    graph_head<<<1, 256, 0, stream>>>(colsum0, colsum1, colsum2,
                                      g0w, g0b, g1w, g1b, g2w, g2b, glw, glb, gvec);
    // out = node2 + gvec
    final_add<<<((size_t)N_NODES * HID / 4 + 255) / 256, 256, 0, stream>>>(node2, gvec, out);
    (void)in_sizes; (void)n_in; (void)out_size; (void)ws_size;
}

// Round 4
// 878.989 us; speedup vs baseline: 2.9425x; 1.1816x over previous
//
#include <hip/hip_runtime.h>

#define N_NODES 50000
#define N_EDGES 800000
#define IN_DIM  162
#define HID     256
#define KPAD1   192   // IN_DIM padded to multiple of 32
#define NB      ((N_NODES + 255) / 256)   // 196 scan blocks

typedef __bf16 bf16;
typedef __bf16 bf16x8 __attribute__((ext_vector_type(8)));
typedef __bf16 bf16x4 __attribute__((ext_vector_type(4)));
typedef float  f32x4  __attribute__((ext_vector_type(4)));

// ---------------------------------------------------------------------------
// Transpose weight W[K][HID] (f32) -> Wt[HID][KPAD] (bf16), zero-pad k>=K.
__global__ void wt_transpose(const float* __restrict__ W, bf16* __restrict__ Wt,
                             int K, int KPAD)
{
    int idx = blockIdx.x * blockDim.x + threadIdx.x;
    int total = HID * KPAD;
    if (idx >= total) return;
    int n = idx / KPAD;
    int k = idx - n * KPAD;
    Wt[idx] = (k < K) ? (bf16)W[(size_t)k * HID + n] : (bf16)0.0f;
}

// ---------------------------------------------------------------------------
// feat f32 [N, IN_DIM] -> featbf bf16 [N, KPAD1] (cols >= IN_DIM zeroed).
__global__ void feat_to_bf16(const float* __restrict__ feat, bf16* __restrict__ featbf)
{
    int idx = blockIdx.x * blockDim.x + threadIdx.x;  // over N*KPAD1/4
    int r = idx / (KPAD1 / 4);
    int c4 = (idx - r * (KPAD1 / 4)) * 4;
    if (r >= N_NODES) return;
    bf16x4 o;
#pragma unroll
    for (int j = 0; j < 4; ++j) {
        int c = c4 + j;
        o[j] = (c < IN_DIM) ? (bf16)feat[(size_t)r * IN_DIM + c] : (bf16)0.0f;
    }
    *(bf16x4*)(featbf + (size_t)r * KPAD1 + c4) = o;
}

// ---------------------------------------------------------------------------
// CSR build, step 1: degree histogram over dst.
__global__ void degree_hist(const int* __restrict__ dst, int* __restrict__ deg)
{
    int e = blockIdx.x * blockDim.x + threadIdx.x;   // grid covers N_EDGES exactly
    atomicAdd(&deg[dst[e]], 1);
}

// CSR build, step 2a: per-block sums of deg (256 elements/block).
__global__ void block_degsum(const int* __restrict__ deg, int* __restrict__ bsum)
{
    __shared__ int s[256];
    int t = threadIdx.x;
    int idx = blockIdx.x * 256 + t;
    int v = (idx < N_NODES) ? deg[idx] : 0;
    s[t] = v;
    __syncthreads();
    for (int off = 128; off > 0; off >>= 1) {
        if (t < off) s[t] += s[t + off];
        __syncthreads();
    }
    if (t == 0) bsum[blockIdx.x] = s[0];
}

// CSR build, step 2b: exclusive scan of the NB block sums (single small block).
__global__ void scan_bsum(const int* __restrict__ bsum, int* __restrict__ gsum)
{
    __shared__ int s[256];
    int t = threadIdx.x;
    int v = (t < NB) ? bsum[t] : 0;
    s[t] = v;
    __syncthreads();
    for (int off = 1; off < 256; off <<= 1) {
        int u = (t >= off) ? s[t - off] : 0;
        __syncthreads();
        s[t] += u;
        __syncthreads();
    }
    gsum[t] = s[t] - v;   // exclusive prefix
}

// CSR build, step 2c: per-block local scan + global offset -> rowptr/cursor.
__global__ void block_scan_write(const int* __restrict__ deg, const int* __restrict__ gsum,
                                 int* __restrict__ rowptr, int* __restrict__ cursor)
{
    __shared__ int s[256];
    int t = threadIdx.x;
    int idx = blockIdx.x * 256 + t;
    int v = (idx < N_NODES) ? deg[idx] : 0;
    s[t] = v;
    __syncthreads();
    for (int off = 1; off < 256; off <<= 1) {
        int u = (t >= off) ? s[t - off] : 0;
        __syncthreads();
        s[t] += u;
        __syncthreads();
    }
    int excl = s[t] - v + gsum[blockIdx.x];
    if (idx < N_NODES) {
        rowptr[idx] = excl;
        cursor[idx] = excl;
    }
    if (idx == 0) rowptr[N_NODES] = N_EDGES;   // every dst is in [0, N)
}

// CSR build, step 3: fill src ids grouped by dst.
__global__ void csr_fill(const int* __restrict__ src, const int* __restrict__ dst,
                         int* __restrict__ cursor, int* __restrict__ csr_src)
{
    int e = blockIdx.x * blockDim.x + threadIdx.x;
    int p = atomicAdd(&cursor[dst[e]], 1);
    csr_src[p] = src[e];
}

// ---------------------------------------------------------------------------
// colsum0[c] = sum_n feat[n][c]; 250 blocks x 192 threads, 200 rows/block.
__global__ void colsum_feat(const float* __restrict__ feat, float* __restrict__ colsum0)
{
    int c  = threadIdx.x;          // 0..191, only <162 active
    int r0 = blockIdx.x * 200;
    if (c >= IN_DIM) return;
    float acc = 0.0f;
    for (int i = 0; i < 200; ++i) {
        int r = r0 + i;
        if (r < N_NODES) acc += feat[(size_t)r * IN_DIM + c];
    }
    atomicAdd(&colsum0[c], acc);
}

// ---------------------------------------------------------------------------
// Gather layer 1 (bf16): xsum[n][:] = bf16( featbf[n][:] + sum featbf[src][:] )
// One wave per node; lanes 0..47 each own 4 consecutive cols (8B loads).
__global__ void gather1(const bf16* __restrict__ featbf,
                        const int* __restrict__ rowptr,
                        const int* __restrict__ csr_src,
                        bf16* __restrict__ xsum)
{
    int wave = threadIdx.x >> 6;
    int lane = threadIdx.x & 63;
    int n = blockIdx.x * 4 + wave;
    if (n >= N_NODES || lane >= KPAD1 / 4) return;

    const int c = lane * 4;
    f32x4 acc;
    bf16x4 t0 = *(const bf16x4*)(featbf + (size_t)n * KPAD1 + c);
#pragma unroll
    for (int j = 0; j < 4; ++j) acc[j] = (float)t0[j];

    int jb = rowptr[n], je = rowptr[n + 1];
    for (; jb + 1 < je; jb += 2) {
        int s0 = csr_src[jb], s1 = csr_src[jb + 1];
        bf16x4 u0 = *(const bf16x4*)(featbf + (size_t)s0 * KPAD1 + c);
        bf16x4 u1 = *(const bf16x4*)(featbf + (size_t)s1 * KPAD1 + c);
#pragma unroll
        for (int j = 0; j < 4; ++j) acc[j] += (float)u0[j] + (float)u1[j];
    }
    if (jb < je) {
        bf16x4 u0 = *(const bf16x4*)(featbf + (size_t)csr_src[jb] * KPAD1 + c);
#pragma unroll
        for (int j = 0; j < 4; ++j) acc[j] += (float)u0[j];
    }
    bf16x4 o;
#pragma unroll
    for (int j = 0; j < 4; ++j) o[j] = (bf16)acc[j];
    *(bf16x4*)(xsum + (size_t)n * KPAD1 + c) = o;
}

// ---------------------------------------------------------------------------
// Gather layer 2: y2[n][0..255] = bf16( node1[n][:] + sum node1[src][:] )
// One wave per node; lane owns 4 consecutive cols (bf16x4 = 8B/lane).
__global__ void gather2(const bf16* __restrict__ node1,
                        const int* __restrict__ rowptr,
                        const int* __restrict__ csr_src,
                        bf16* __restrict__ y2)
{
    int wave = threadIdx.x >> 6;
    int lane = threadIdx.x & 63;
    int n = blockIdx.x * 4 + wave;
    if (n >= N_NODES) return;

    const int c = lane * 4;
    f32x4 acc;
    bf16x4 t0 = *(const bf16x4*)(node1 + (size_t)n * HID + c);
#pragma unroll
    for (int j = 0; j < 4; ++j) acc[j] = (float)t0[j];

    int jb = rowptr[n], je = rowptr[n + 1];
    for (; jb + 1 < je; jb += 2) {
        int s0 = csr_src[jb], s1 = csr_src[jb + 1];
        bf16x4 u0 = *(const bf16x4*)(node1 + (size_t)s0 * HID + c);
        bf16x4 u1 = *(const bf16x4*)(node1 + (size_t)s1 * HID + c);
#pragma unroll
        for (int j = 0; j < 4; ++j) acc[j] += (float)u0[j] + (float)u1[j];
    }
    if (jb < je) {
        bf16x4 u0 = *(const bf16x4*)(node1 + (size_t)csr_src[jb] * HID + c);
#pragma unroll
        for (int j = 0; j < 4; ++j) acc[j] += (float)u0[j];
    }
    bf16x4 o;
#pragma unroll
    for (int j = 0; j < 4; ++j) o[j] = (bf16)acc[j];
    *(bf16x4*)(y2 + (size_t)n * HID + c) = o;
}

// ---------------------------------------------------------------------------
// GEMM: out = relu(X[M,KPAD](bf16) @ W + bias) via Wt[HID][KPAD] (bf16).
// Block = 4 waves; tile 64 rows x 256 cols; wave owns 16 rows x 256 cols.
// A-frag: lane holds row (lane&15), k = (lane>>4)*8 + j   [m89-verified]
// B-frag: lane holds col (lane&15), k = (lane>>4)*8 + j
// D:      lane holds col (lane&15), rows (lane>>4)*4 + r
template<int KPAD>
__launch_bounds__(256)
__global__ void gemm_relu(const bf16* __restrict__ X,
                          const bf16* __restrict__ Wt,      // [HID][KPAD]
                          const float* __restrict__ bias,   // [HID]
                          bf16*  __restrict__ out_bf,       // nullable
                          float* __restrict__ out_f32,      // nullable
                          int M)
{
    const int tid  = threadIdx.x;
    const int w    = tid >> 6;
    const int lane = tid & 63;
    const int q    = lane >> 4;
    const int ln   = lane & 15;
    const int m_base = blockIdx.x * 64 + w * 16;

    int m = m_base + ln;
    if (m >= M) m = M - 1;   // clamp (stores guarded)

    f32x4 acc[16];
#pragma unroll
    for (int t = 0; t < 16; ++t)
#pragma unroll
        for (int r = 0; r < 4; ++r) acc[t][r] = 0.0f;

    for (int k0 = 0; k0 < KPAD; k0 += 32) {
        bf16x8 a = *(const bf16x8*)(X + (size_t)m * KPAD + k0 + q * 8);
#pragma unroll
        for (int t = 0; t < 16; ++t) {
            bf16x8 b = *(const bf16x8*)(Wt + (size_t)(t * 16 + ln) * KPAD + k0 + q * 8);
            acc[t] = __builtin_amdgcn_mfma_f32_16x16x32_bf16(a, b, acc[t], 0, 0, 0);
        }
    }

    const int row0 = m_base + q * 4;
#pragma unroll
    for (int t = 0; t < 16; ++t) {
        const int c = t * 16 + ln;
        const float bv = bias[c];
#pragma unroll
        for (int r = 0; r < 4; ++r) {
            int mo = row0 + r;
            if (mo < M) {
                float v = acc[t][r] + bv;
                v = v > 0.0f ? v : 0.0f;
                if (out_bf)  out_bf[(size_t)mo * HID + c]  = (bf16)v;
                if (out_f32) out_f32[(size_t)mo * HID + c] = v;
            }
        }
    }
}

// ---------------------------------------------------------------------------
// Column sum of a [M, HID] matrix into out[HID] (pre-zeroed).
template<bool BF>
__global__ void colsum_kernel(const void* __restrict__ in, float* __restrict__ out,
                              int M, int rows_per_block)
{
    int c  = threadIdx.x;   // 256
    int r0 = blockIdx.x * rows_per_block;
    float acc = 0.0f;
    for (int i = 0; i < rows_per_block; ++i) {
        int r = r0 + i;
        if (r < M) {
            if (BF) acc += (float)((const bf16*)in)[(size_t)r * HID + c];
            else    acc += ((const float*)in)[(size_t)r * HID + c];
        }
    }
    atomicAdd(&out[c], acc);
}

// ---------------------------------------------------------------------------
// Graph head: three GEMVs + sum + final GEMV, single block of 256 threads.
__global__ void graph_head(const float* __restrict__ cs0,
                           const float* __restrict__ cs1,
                           const float* __restrict__ cs2,
                           const float* __restrict__ g0w, const float* __restrict__ g0b,
                           const float* __restrict__ g1w, const float* __restrict__ g1b,
                           const float* __restrict__ g2w, const float* __restrict__ g2b,
                           const float* __restrict__ glw, const float* __restrict__ glb,
                           float* __restrict__ gvec)
{
    __shared__ float v0[IN_DIM], v1[HID], v2[HID], gs[HID];
    int t = threadIdx.x;
    if (t < IN_DIM) v0[t] = cs0[t];
    v1[t] = cs1[t];
    v2[t] = cs2[t];
    __syncthreads();

    float a0 = 0.0f, a1 = 0.0f, a2 = 0.0f;
    for (int k = 0; k < IN_DIM; ++k) a0 += v0[k] * g0w[k * HID + t];
    for (int k = 0; k < HID; ++k) {
        a1 += v1[k] * g1w[k * HID + t];
        a2 += v2[k] * g2w[k * HID + t];
    }
    float e0 = fmaxf(a0 + g0b[t], 0.0f);
    float e1 = fmaxf(a1 + g1b[t], 0.0f);
    float e2 = fmaxf(a2 + g2b[t], 0.0f);
    gs[t] = e0 + e1 + e2;
    __syncthreads();

    float a3 = 0.0f;
    for (int k = 0; k < HID; ++k) a3 += gs[k] * glw[k * HID + t];
    gvec[t] = fmaxf(a3 + glb[t], 0.0f);
}

// ---------------------------------------------------------------------------
// out[n,c] = node2[n,c] + gvec[c] (f32); 4 elements per thread.
__global__ void final_add(const float* __restrict__ node2,
                          const float* __restrict__ gvec,
                          float* __restrict__ out)
{
    int idx = blockIdx.x * blockDim.x + threadIdx.x;
    size_t base = (size_t)idx * 4;
    int c = (int)(base & (HID - 1));
    f32x4 v = *(const f32x4*)(node2 + base);
    f32x4 g = *(const f32x4*)(gvec + c);
    f32x4 o;
#pragma unroll
    for (int j = 0; j < 4; ++j) o[j] = v[j] + g[j];
    *(f32x4*)(out + base) = o;
}

// ---------------------------------------------------------------------------
extern "C" void kernel_launch(void* const* d_in, const int* in_sizes, int n_in,
                              void* d_out, int out_size, void* d_ws, size_t ws_size,
                              hipStream_t stream)
{
    const float* feat = (const float*)d_in[0];
    const int*   ei   = (const int*)d_in[1];
    const int*   src  = ei;
    const int*   dst  = ei + N_EDGES;
    const float* g0w = (const float*)d_in[2],  *g0b = (const float*)d_in[3];
    const float* g1w = (const float*)d_in[4],  *g1b = (const float*)d_in[5];
    const float* g2w = (const float*)d_in[6],  *g2b = (const float*)d_in[7];
    const float* glw = (const float*)d_in[8],  *glb = (const float*)d_in[9];
    const float* m1aw = (const float*)d_in[10], *m1ab = (const float*)d_in[11];
    const float* m1bw = (const float*)d_in[12], *m1bb = (const float*)d_in[13];
    const float* m2aw = (const float*)d_in[14], *m2ab = (const float*)d_in[15];
    const float* m2bw = (const float*)d_in[16], *m2bb = (const float*)d_in[17];
    float* out = (float*)d_out;

    char* ws = (char*)d_ws;
    size_t off = 0;
    auto alloc = [&](size_t bytes) -> void* {
        void* p = ws + off;
        off += (bytes + 255) & ~(size_t)255;
        return p;
    };
    bf16*  featbf = (bf16*)alloc((size_t)N_NODES * KPAD1 * 2); // bf16(feat), padded
    bf16*  xsum  = (bf16*) alloc((size_t)N_NODES * KPAD1 * 2); // bf16(x+agg1)
    bf16*  y2    = (bf16*) alloc((size_t)N_NODES * HID * 2);   // bf16(node1+agg2)
    float* node2 = (float*)alloc((size_t)N_NODES * HID * 4);
    bf16*  h1    = (bf16*) alloc((size_t)N_NODES * HID * 2);   // reused as h2
    bf16*  node1 = (bf16*) alloc((size_t)N_NODES * HID * 2);
    bf16*  Wt1   = (bf16*) alloc((size_t)HID * KPAD1 * 2);
    bf16*  Wt2   = (bf16*) alloc((size_t)HID * HID * 2);
    bf16*  Wt3   = (bf16*) alloc((size_t)HID * HID * 2);
    bf16*  Wt4   = (bf16*) alloc((size_t)HID * HID * 2);
    int*   deg     = (int*)alloc((size_t)N_NODES * 4);
    int*   rowptr  = (int*)alloc((size_t)(N_NODES + 1) * 4);
    int*   cursor  = (int*)alloc((size_t)N_NODES * 4);
    int*   csr_src = (int*)alloc((size_t)N_EDGES * 4);
    int*   bsum    = (int*)alloc(256 * 4);
    int*   gsum    = (int*)alloc(256 * 4);
    float* csums = (float*)alloc((192 + 256 + 256 + 256) * 4);
    float* colsum0 = csums;            // 192 (162 used)
    float* colsum1 = csums + 192;      // 256
    float* colsum2 = csums + 448;      // 256
    float* gvec    = csums + 704;      // 256

    hipMemsetAsync(csums, 0, 704 * 4, stream);
    hipMemsetAsync(deg, 0, (size_t)N_NODES * 4, stream);

    // weight transposes (tiny)
    wt_transpose<<<(HID * KPAD1 + 255) / 256, 256, 0, stream>>>(m1aw, Wt1, IN_DIM, KPAD1);
    wt_transpose<<<(HID * HID + 255) / 256, 256, 0, stream>>>(m1bw, Wt2, HID, HID);
    wt_transpose<<<(HID * HID + 255) / 256, 256, 0, stream>>>(m2aw, Wt3, HID, HID);
    wt_transpose<<<(HID * HID + 255) / 256, 256, 0, stream>>>(m2bw, Wt4, HID, HID);

    // feat -> bf16 padded
    feat_to_bf16<<<((size_t)N_NODES * (KPAD1 / 4) + 255) / 256, 256, 0, stream>>>(feat, featbf);

    // CSR build (grouped by dst) — hierarchical scan
    degree_hist<<<N_EDGES / 256, 256, 0, stream>>>(dst, deg);
    block_degsum<<<NB, 256, 0, stream>>>(deg, bsum);
    scan_bsum<<<1, 256, 0, stream>>>(bsum, gsum);
    block_scan_write<<<NB, 256, 0, stream>>>(deg, gsum, rowptr, cursor);
    csr_fill<<<N_EDGES / 256, 256, 0, stream>>>(src, dst, cursor, csr_src);

    // colsum0 = sum(feat, axis=0)  (f32 exact path)
    colsum_feat<<<250, 192, 0, stream>>>(feat, colsum0);

    // xsum = bf16(feat + gather(feat))
    gather1<<<(N_NODES + 3) / 4, 256, 0, stream>>>(featbf, rowptr, csr_src, xsum);

    const int gblocks = (N_NODES + 63) / 64;
    // h1 = relu(xsum @ m1a_w + b)
    gemm_relu<KPAD1><<<gblocks, 256, 0, stream>>>(xsum, Wt1, m1ab, h1, nullptr, N_NODES);
    // node1 = relu(h1 @ m1b_w + b)
    gemm_relu<HID><<<gblocks, 256, 0, stream>>>(h1, Wt2, m1bb, node1, nullptr, N_NODES);
    // colsum1 = sum(node1, axis=0)
    colsum_kernel<true><<<250, 256, 0, stream>>>(node1, colsum1, N_NODES, 200);
    // y2 = bf16(node1 + gather(node1))
    gather2<<<(N_NODES + 3) / 4, 256, 0, stream>>>(node1, rowptr, csr_src, y2);
    // h2 = relu(y2 @ m2a_w + b)  (reuse h1 buffer)
    gemm_relu<HID><<<gblocks, 256, 0, stream>>>(y2, Wt3, m2ab, h1, nullptr, N_NODES);
    // node2 = relu(h2 @ m2b_w + b) (f32)
    gemm_relu<HID><<<gblocks, 256, 0, stream>>>(h1, Wt4, m2bb, nullptr, node2, N_NODES);
    // colsum2 = sum(node2, axis=0)
    colsum_kernel<false><<<250, 256, 0, stream>>>(node2, colsum2, N_NODES, 200);
    // graph head -> gvec = g_last
    graph_head<<<1, 256, 0, stream>>>(colsum0, colsum1, colsum2,
                                      g0w, g0b, g1w, g1b, g2w, g2b, glw, glb, gvec);
    // out = node2 + gvec
    final_add<<<((size_t)N_NODES * HID / 4 + 255) / 256, 256, 0, stream>>>(node2, gvec, out);
    (void)in_sizes; (void)n_in; (void)out_size; (void)ws_size;
}

// Round 5
// 693.821 us; speedup vs baseline: 3.7277x; 1.2669x over previous
//
#include <hip/hip_runtime.h>

#define N_NODES 50000
#define N_EDGES 800000
#define IN_DIM  162
#define HID     256
#define KPAD1   192   // IN_DIM padded to multiple of 32
#define NB      ((N_NODES + 255) / 256)   // 196 scan blocks

typedef __bf16 bf16;
typedef __bf16 bf16x8 __attribute__((ext_vector_type(8)));
typedef __bf16 bf16x4 __attribute__((ext_vector_type(4)));
typedef float  f32x4  __attribute__((ext_vector_type(4)));
typedef float  f32x16 __attribute__((ext_vector_type(16)));

#define GLDS16(g, l) __builtin_amdgcn_global_load_lds( \
    (const __attribute__((address_space(1))) void*)(g), \
    (__attribute__((address_space(3))) void*)(l), 16, 0, 0)

// ---------------------------------------------------------------------------
// Transpose weight W[K][HID] (f32) -> Wt[HID][KPAD] (bf16), zero-pad k>=K.
__global__ void wt_transpose(const float* __restrict__ W, bf16* __restrict__ Wt,
                             int K, int KPAD)
{
    int idx = blockIdx.x * blockDim.x + threadIdx.x;
    int total = HID * KPAD;
    if (idx >= total) return;
    int n = idx / KPAD;
    int k = idx - n * KPAD;
    Wt[idx] = (k < K) ? (bf16)W[(size_t)k * HID + n] : (bf16)0.0f;
}

// ---------------------------------------------------------------------------
// feat f32 [N, IN_DIM] -> featbf bf16 [N, KPAD1] (cols >= IN_DIM zeroed).
__global__ void feat_to_bf16(const float* __restrict__ feat, bf16* __restrict__ featbf)
{
    int idx = blockIdx.x * blockDim.x + threadIdx.x;  // over N*KPAD1/4
    int r = idx / (KPAD1 / 4);
    int c4 = (idx - r * (KPAD1 / 4)) * 4;
    if (r >= N_NODES) return;
    bf16x4 o;
#pragma unroll
    for (int j = 0; j < 4; ++j) {
        int c = c4 + j;
        o[j] = (c < IN_DIM) ? (bf16)feat[(size_t)r * IN_DIM + c] : (bf16)0.0f;
    }
    *(bf16x4*)(featbf + (size_t)r * KPAD1 + c4) = o;
}

// ---------------------------------------------------------------------------
// CSR build, step 1: degree histogram over dst.
__global__ void degree_hist(const int* __restrict__ dst, int* __restrict__ deg)
{
    int e = blockIdx.x * blockDim.x + threadIdx.x;
    atomicAdd(&deg[dst[e]], 1);
}

// CSR build, step 2a: per-block sums of deg (256 elements/block).
__global__ void block_degsum(const int* __restrict__ deg, int* __restrict__ bsum)
{
    __shared__ int s[256];
    int t = threadIdx.x;
    int idx = blockIdx.x * 256 + t;
    int v = (idx < N_NODES) ? deg[idx] : 0;
    s[t] = v;
    __syncthreads();
    for (int off = 128; off > 0; off >>= 1) {
        if (t < off) s[t] += s[t + off];
        __syncthreads();
    }
    if (t == 0) bsum[blockIdx.x] = s[0];
}

// CSR build, step 2b: exclusive scan of the NB block sums (single small block).
__global__ void scan_bsum(const int* __restrict__ bsum, int* __restrict__ gsum)
{
    __shared__ int s[256];
    int t = threadIdx.x;
    int v = (t < NB) ? bsum[t] : 0;
    s[t] = v;
    __syncthreads();
    for (int off = 1; off < 256; off <<= 1) {
        int u = (t >= off) ? s[t - off] : 0;
        __syncthreads();
        s[t] += u;
        __syncthreads();
    }
    gsum[t] = s[t] - v;
}

// CSR build, step 2c: per-block local scan + global offset -> rowptr/cursor.
__global__ void block_scan_write(const int* __restrict__ deg, const int* __restrict__ gsum,
                                 int* __restrict__ rowptr, int* __restrict__ cursor)
{
    __shared__ int s[256];
    int t = threadIdx.x;
    int idx = blockIdx.x * 256 + t;
    int v = (idx < N_NODES) ? deg[idx] : 0;
    s[t] = v;
    __syncthreads();
    for (int off = 1; off < 256; off <<= 1) {
        int u = (t >= off) ? s[t - off] : 0;
        __syncthreads();
        s[t] += u;
        __syncthreads();
    }
    int excl = s[t] - v + gsum[blockIdx.x];
    if (idx < N_NODES) {
        rowptr[idx] = excl;
        cursor[idx] = excl;
    }
    if (idx == 0) rowptr[N_NODES] = N_EDGES;
}

// CSR build, step 3: fill src ids grouped by dst.
__global__ void csr_fill(const int* __restrict__ src, const int* __restrict__ dst,
                         int* __restrict__ cursor, int* __restrict__ csr_src)
{
    int e = blockIdx.x * blockDim.x + threadIdx.x;
    int p = atomicAdd(&cursor[dst[e]], 1);
    csr_src[p] = src[e];
}

// ---------------------------------------------------------------------------
// colsum0[c] = sum_n feat[n][c]; 250 blocks x 192 threads, 200 rows/block.
__global__ void colsum_feat(const float* __restrict__ feat, float* __restrict__ colsum0)
{
    int c  = threadIdx.x;
    int r0 = blockIdx.x * 200;
    if (c >= IN_DIM) return;
    float acc = 0.0f;
    for (int i = 0; i < 200; ++i) {
        int r = r0 + i;
        if (r < N_NODES) acc += feat[(size_t)r * IN_DIM + c];
    }
    atomicAdd(&colsum0[c], acc);
}

// ---------------------------------------------------------------------------
// Gather layer 1 (bf16): xsum[n][:] = bf16( featbf[n][:] + sum featbf[src][:] )
__global__ void gather1(const bf16* __restrict__ featbf,
                        const int* __restrict__ rowptr,
                        const int* __restrict__ csr_src,
                        bf16* __restrict__ xsum)
{
    int wave = threadIdx.x >> 6;
    int lane = threadIdx.x & 63;
    int n = blockIdx.x * 4 + wave;
    if (n >= N_NODES || lane >= KPAD1 / 4) return;

    const int c = lane * 4;
    f32x4 acc;
    bf16x4 t0 = *(const bf16x4*)(featbf + (size_t)n * KPAD1 + c);
#pragma unroll
    for (int j = 0; j < 4; ++j) acc[j] = (float)t0[j];

    int jb = rowptr[n], je = rowptr[n + 1];
    for (; jb + 1 < je; jb += 2) {
        int s0 = csr_src[jb], s1 = csr_src[jb + 1];
        bf16x4 u0 = *(const bf16x4*)(featbf + (size_t)s0 * KPAD1 + c);
        bf16x4 u1 = *(const bf16x4*)(featbf + (size_t)s1 * KPAD1 + c);
#pragma unroll
        for (int j = 0; j < 4; ++j) acc[j] += (float)u0[j] + (float)u1[j];
    }
    if (jb < je) {
        bf16x4 u0 = *(const bf16x4*)(featbf + (size_t)csr_src[jb] * KPAD1 + c);
#pragma unroll
        for (int j = 0; j < 4; ++j) acc[j] += (float)u0[j];
    }
    bf16x4 o;
#pragma unroll
    for (int j = 0; j < 4; ++j) o[j] = (bf16)acc[j];
    *(bf16x4*)(xsum + (size_t)n * KPAD1 + c) = o;
}

// ---------------------------------------------------------------------------
// Gather layer 2: y2[n][0..255] = bf16( node1[n][:] + sum node1[src][:] )
__global__ void gather2(const bf16* __restrict__ node1,
                        const int* __restrict__ rowptr,
                        const int* __restrict__ csr_src,
                        bf16* __restrict__ y2)
{
    int wave = threadIdx.x >> 6;
    int lane = threadIdx.x & 63;
    int n = blockIdx.x * 4 + wave;
    if (n >= N_NODES) return;

    const int c = lane * 4;
    f32x4 acc;
    bf16x4 t0 = *(const bf16x4*)(node1 + (size_t)n * HID + c);
#pragma unroll
    for (int j = 0; j < 4; ++j) acc[j] = (float)t0[j];

    int jb = rowptr[n], je = rowptr[n + 1];
    for (; jb + 1 < je; jb += 2) {
        int s0 = csr_src[jb], s1 = csr_src[jb + 1];
        bf16x4 u0 = *(const bf16x4*)(node1 + (size_t)s0 * HID + c);
        bf16x4 u1 = *(const bf16x4*)(node1 + (size_t)s1 * HID + c);
#pragma unroll
        for (int j = 0; j < 4; ++j) acc[j] += (float)u0[j] + (float)u1[j];
    }
    if (jb < je) {
        bf16x4 u0 = *(const bf16x4*)(node1 + (size_t)csr_src[jb] * HID + c);
#pragma unroll
        for (int j = 0; j < 4; ++j) acc[j] += (float)u0[j];
    }
    bf16x4 o;
#pragma unroll
    for (int j = 0; j < 4; ++j) o[j] = (bf16)acc[j];
    *(bf16x4*)(y2 + (size_t)n * HID + c) = o;
}

// ---------------------------------------------------------------------------
// GEMM v2: out = relu(X[M,KPAD](bf16) @ W + bias), Wt[HID][KPAD] bf16.
// Block = 4 waves, tile 128 rows x 256 cols; wave w owns rows [w*32, w*32+32)
// x all 256 cols = 8 tiles of mfma_f32_32x32x16_bf16 (acc 8 x 16 f32).
// Wt k-slice (256 cols x 32 k = 16 KB) staged frag-major in LDS via
// global_load_lds width=16: frag-block fb=(j,kk) is 1 KB, lane's 16B at
// lane*16 -> conflict-free stride-16 ds_read_b128.
// A-frag: row = lane&31, k = (lane>>5)*8 + j
// B-frag: col = lane&31, k = (lane>>5)*8 + j
// C/D  : col = lane&31, row = (reg&3) + 8*(reg>>2) + 4*(lane>>5)  [m74/m101]
template<int KPAD>
__launch_bounds__(256)
__global__ void gemm_relu2(const bf16* __restrict__ X,
                           const bf16* __restrict__ Wt,
                           const float* __restrict__ bias,
                           bf16* __restrict__ out_bf,
                           int M)
{
    __shared__ __align__(128) bf16 sB[8192];   // 16 KB = 16 frag-blocks x 1 KB

    const int tid  = threadIdx.x;
    const int w    = tid >> 6;
    const int lane = tid & 63;
    const int p    = lane >> 5;    // 0..1 (k-half)
    const int cn   = lane & 31;
    const int m_base = blockIdx.x * 128 + w * 32;

    int arow = m_base + cn;
    if (arow >= M) arow = M - 1;   // clamp (stores guarded)

    f32x16 acc[8];
#pragma unroll
    for (int j = 0; j < 8; ++j)
#pragma unroll
        for (int r = 0; r < 16; ++r) acc[j][r] = 0.0f;

    for (int k0 = 0; k0 < KPAD; k0 += 32) {
        __syncthreads();   // protect LDS from previous iteration's readers
        // wave w stages frag-blocks fb = w*4 .. w*4+3
#pragma unroll
        for (int i = 0; i < 4; ++i) {
            int fb = w * 4 + i;
            int j  = fb >> 1;      // col tile 0..7
            int kk = fb & 1;       // k16 half
            const bf16* g = Wt + (size_t)(j * 32 + cn) * KPAD + k0 + kk * 16 + p * 8;
            GLDS16(g, sB + fb * 512);
        }
        __syncthreads();   // vmcnt(0) drain implied before barrier

#pragma unroll
        for (int kk = 0; kk < 2; ++kk) {
            bf16x8 a = *(const bf16x8*)(X + (size_t)arow * KPAD + k0 + kk * 16 + p * 8);
#pragma unroll
            for (int j = 0; j < 8; ++j) {
                bf16x8 b = *(const bf16x8*)(sB + (j * 2 + kk) * 512 + lane * 8);
                acc[j] = __builtin_amdgcn_mfma_f32_32x32x16_bf16(a, b, acc[j], 0, 0, 0);
            }
        }
    }

#pragma unroll
    for (int j = 0; j < 8; ++j) {
        const int col = j * 32 + cn;
        const float bv = bias[col];
#pragma unroll
        for (int r = 0; r < 16; ++r) {
            int rl = (r & 3) + 8 * (r >> 2) + 4 * p;
            int mo = m_base + rl;
            if (mo < M) {
                float v = acc[j][r] + bv;
                v = v > 0.0f ? v : 0.0f;
                out_bf[(size_t)mo * HID + col] = (bf16)v;
            }
        }
    }
}

// ---------------------------------------------------------------------------
// Column sum of a bf16 [M, HID] matrix into out[HID] (pre-zeroed).
__global__ void colsum_kernel(const bf16* __restrict__ in, float* __restrict__ out,
                              int M, int rows_per_block)
{
    int c  = threadIdx.x;   // 256
    int r0 = blockIdx.x * rows_per_block;
    float acc = 0.0f;
    for (int i = 0; i < rows_per_block; ++i) {
        int r = r0 + i;
        if (r < M) acc += (float)in[(size_t)r * HID + c];
    }
    atomicAdd(&out[c], acc);
}

// ---------------------------------------------------------------------------
// Graph head: three GEMVs + sum + final GEMV, single block of 256 threads.
__global__ void graph_head(const float* __restrict__ cs0,
                           const float* __restrict__ cs1,
                           const float* __restrict__ cs2,
                           const float* __restrict__ g0w, const float* __restrict__ g0b,
                           const float* __restrict__ g1w, const float* __restrict__ g1b,
                           const float* __restrict__ g2w, const float* __restrict__ g2b,
                           const float* __restrict__ glw, const float* __restrict__ glb,
                           float* __restrict__ gvec)
{
    __shared__ float v0[IN_DIM], v1[HID], v2[HID], gs[HID];
    int t = threadIdx.x;
    if (t < IN_DIM) v0[t] = cs0[t];
    v1[t] = cs1[t];
    v2[t] = cs2[t];
    __syncthreads();

    float a0 = 0.0f, a1 = 0.0f, a2 = 0.0f;
    for (int k = 0; k < IN_DIM; ++k) a0 += v0[k] * g0w[k * HID + t];
    for (int k = 0; k < HID; ++k) {
        a1 += v1[k] * g1w[k * HID + t];
        a2 += v2[k] * g2w[k * HID + t];
    }
    float e0 = fmaxf(a0 + g0b[t], 0.0f);
    float e1 = fmaxf(a1 + g1b[t], 0.0f);
    float e2 = fmaxf(a2 + g2b[t], 0.0f);
    gs[t] = e0 + e1 + e2;
    __syncthreads();

    float a3 = 0.0f;
    for (int k = 0; k < HID; ++k) a3 += gs[k] * glw[k * HID + t];
    gvec[t] = fmaxf(a3 + glb[t], 0.0f);
}

// ---------------------------------------------------------------------------
// out[n,c] = node2[n,c](bf16) + gvec[c] (f32 out); 4 elements per thread.
__global__ void final_add(const bf16* __restrict__ node2,
                          const float* __restrict__ gvec,
                          float* __restrict__ out)
{
    int idx = blockIdx.x * blockDim.x + threadIdx.x;
    size_t base = (size_t)idx * 4;
    int c = (int)(base & (HID - 1));
    bf16x4 v = *(const bf16x4*)(node2 + base);
    f32x4 g = *(const f32x4*)(gvec + c);
    f32x4 o;
#pragma unroll
    for (int j = 0; j < 4; ++j) o[j] = (float)v[j] + g[j];
    *(f32x4*)(out + base) = o;
}

// ---------------------------------------------------------------------------
extern "C" void kernel_launch(void* const* d_in, const int* in_sizes, int n_in,
                              void* d_out, int out_size, void* d_ws, size_t ws_size,
                              hipStream_t stream)
{
    const float* feat = (const float*)d_in[0];
    const int*   ei   = (const int*)d_in[1];
    const int*   src  = ei;
    const int*   dst  = ei + N_EDGES;
    const float* g0w = (const float*)d_in[2],  *g0b = (const float*)d_in[3];
    const float* g1w = (const float*)d_in[4],  *g1b = (const float*)d_in[5];
    const float* g2w = (const float*)d_in[6],  *g2b = (const float*)d_in[7];
    const float* glw = (const float*)d_in[8],  *glb = (const float*)d_in[9];
    const float* m1aw = (const float*)d_in[10], *m1ab = (const float*)d_in[11];
    const float* m1bw = (const float*)d_in[12], *m1bb = (const float*)d_in[13];
    const float* m2aw = (const float*)d_in[14], *m2ab = (const float*)d_in[15];
    const float* m2bw = (const float*)d_in[16], *m2bb = (const float*)d_in[17];
    float* out = (float*)d_out;

    char* ws = (char*)d_ws;
    size_t off = 0;
    auto alloc = [&](size_t bytes) -> void* {
        void* p = ws + off;
        off += (bytes + 255) & ~(size_t)255;
        return p;
    };
    bf16*  featbf = (bf16*)alloc((size_t)N_NODES * KPAD1 * 2);
    bf16*  xsum  = (bf16*) alloc((size_t)N_NODES * KPAD1 * 2);
    bf16*  y2    = (bf16*) alloc((size_t)N_NODES * HID * 2);
    bf16*  node2 = (bf16*) alloc((size_t)N_NODES * HID * 2);
    bf16*  h1    = (bf16*) alloc((size_t)N_NODES * HID * 2);   // reused as h2
    bf16*  node1 = (bf16*) alloc((size_t)N_NODES * HID * 2);
    bf16*  Wt1   = (bf16*) alloc((size_t)HID * KPAD1 * 2);
    bf16*  Wt2   = (bf16*) alloc((size_t)HID * HID * 2);
    bf16*  Wt3   = (bf16*) alloc((size_t)HID * HID * 2);
    bf16*  Wt4   = (bf16*) alloc((size_t)HID * HID * 2);
    int*   deg     = (int*)alloc((size_t)N_NODES * 4);
    int*   rowptr  = (int*)alloc((size_t)(N_NODES + 1) * 4);
    int*   cursor  = (int*)alloc((size_t)N_NODES * 4);
    int*   csr_src = (int*)alloc((size_t)N_EDGES * 4);
    int*   bsum    = (int*)alloc(256 * 4);
    int*   gsum    = (int*)alloc(256 * 4);
    float* csums = (float*)alloc((192 + 256 + 256 + 256) * 4);
    float* colsum0 = csums;            // 192 (162 used)
    float* colsum1 = csums + 192;      // 256
    float* colsum2 = csums + 448;      // 256
    float* gvec    = csums + 704;      // 256

    hipMemsetAsync(csums, 0, 704 * 4, stream);
    hipMemsetAsync(deg, 0, (size_t)N_NODES * 4, stream);

    // weight transposes (tiny)
    wt_transpose<<<(HID * KPAD1 + 255) / 256, 256, 0, stream>>>(m1aw, Wt1, IN_DIM, KPAD1);
    wt_transpose<<<(HID * HID + 255) / 256, 256, 0, stream>>>(m1bw, Wt2, HID, HID);
    wt_transpose<<<(HID * HID + 255) / 256, 256, 0, stream>>>(m2aw, Wt3, HID, HID);
    wt_transpose<<<(HID * HID + 255) / 256, 256, 0, stream>>>(m2bw, Wt4, HID, HID);

    // feat -> bf16 padded
    feat_to_bf16<<<((size_t)N_NODES * (KPAD1 / 4) + 255) / 256, 256, 0, stream>>>(feat, featbf);

    // CSR build (grouped by dst) — hierarchical scan
    degree_hist<<<N_EDGES / 256, 256, 0, stream>>>(dst, deg);
    block_degsum<<<NB, 256, 0, stream>>>(deg, bsum);
    scan_bsum<<<1, 256, 0, stream>>>(bsum, gsum);
    block_scan_write<<<NB, 256, 0, stream>>>(deg, gsum, rowptr, cursor);
    csr_fill<<<N_EDGES / 256, 256, 0, stream>>>(src, dst, cursor, csr_src);

    // colsum0 = sum(feat, axis=0)  (f32 exact path)
    colsum_feat<<<250, 192, 0, stream>>>(feat, colsum0);

    // xsum = bf16(feat + gather(feat))
    gather1<<<(N_NODES + 3) / 4, 256, 0, stream>>>(featbf, rowptr, csr_src, xsum);

    const int gblocks = (N_NODES + 127) / 128;
    // h1 = relu(xsum @ m1a_w + b)
    gemm_relu2<KPAD1><<<gblocks, 256, 0, stream>>>(xsum, Wt1, m1ab, h1, N_NODES);
    // node1 = relu(h1 @ m1b_w + b)
    gemm_relu2<HID><<<gblocks, 256, 0, stream>>>(h1, Wt2, m1bb, node1, N_NODES);
    // colsum1 = sum(node1, axis=0)
    colsum_kernel<<<250, 256, 0, stream>>>(node1, colsum1, N_NODES, 200);
    // y2 = bf16(node1 + gather(node1))
    gather2<<<(N_NODES + 3) / 4, 256, 0, stream>>>(node1, rowptr, csr_src, y2);
    // h2 = relu(y2 @ m2a_w + b)  (reuse h1 buffer)
    gemm_relu2<HID><<<gblocks, 256, 0, stream>>>(y2, Wt3, m2ab, h1, N_NODES);
    // node2 = relu(h2 @ m2b_w + b) (bf16 now)
    gemm_relu2<HID><<<gblocks, 256, 0, stream>>>(h1, Wt4, m2bb, node2, N_NODES);
    // colsum2 = sum(node2, axis=0)
    colsum_kernel<<<250, 256, 0, stream>>>(node2, colsum2, N_NODES, 200);
    // graph head -> gvec = g_last
    graph_head<<<1, 256, 0, stream>>>(colsum0, colsum1, colsum2,
                                      g0w, g0b, g1w, g1b, g2w, g2b, glw, glb, gvec);
    // out = node2 + gvec
    final_add<<<((size_t)N_NODES * HID / 4 + 255) / 256, 256, 0, stream>>>(node2, gvec, out);
    (void)in_sizes; (void)n_in; (void)out_size; (void)ws_size;
}

// Round 6
// 597.156 us; speedup vs baseline: 4.3312x; 1.1619x over previous
//
#include <hip/hip_runtime.h>

#define N_NODES 50000
#define N_EDGES 800000
#define IN_DIM  162
#define HID     256
#define KPAD1   192   // IN_DIM padded to multiple of 32
#define NB      ((N_NODES + 255) / 256)   // 196 scan blocks

typedef __bf16 bf16;
typedef __bf16 bf16x8 __attribute__((ext_vector_type(8)));
typedef __bf16 bf16x4 __attribute__((ext_vector_type(4)));
typedef float  f32x4  __attribute__((ext_vector_type(4)));
typedef float  f32x8  __attribute__((ext_vector_type(8)));
typedef float  f32x16 __attribute__((ext_vector_type(16)));

#define GLDS16(g, l) __builtin_amdgcn_global_load_lds( \
    (const __attribute__((address_space(1))) void*)(g), \
    (__attribute__((address_space(3))) void*)(l), 16, 0, 0)

// ---------------------------------------------------------------------------
// All 4 weight transposes in one launch. W[K][HID] f32 -> Wt[HID][KPAD] bf16.
__device__ __forceinline__ void wt_one(const float* W, bf16* Wt, int K, int KPAD, int idx)
{
    int n = idx / KPAD;
    int k = idx - n * KPAD;
    Wt[idx] = (k < K) ? (bf16)W[(size_t)k * HID + n] : (bf16)0.0f;
}

__global__ void wt_transpose_all(const float* __restrict__ m1aw, const float* __restrict__ m1bw,
                                 const float* __restrict__ m2aw, const float* __restrict__ m2bw,
                                 bf16* __restrict__ Wt1, bf16* __restrict__ Wt2,
                                 bf16* __restrict__ Wt3, bf16* __restrict__ Wt4)
{
    const int R1 = HID * KPAD1;          // 49152
    const int R2 = HID * HID;            // 65536
    int idx = blockIdx.x * blockDim.x + threadIdx.x;
    if (idx < R1)                 wt_one(m1aw, Wt1, IN_DIM, KPAD1, idx);
    else if (idx < R1 + R2)       wt_one(m1bw, Wt2, HID, HID, idx - R1);
    else if (idx < R1 + 2 * R2)   wt_one(m2aw, Wt3, HID, HID, idx - R1 - R2);
    else if (idx < R1 + 3 * R2)   wt_one(m2bw, Wt4, HID, HID, idx - R1 - 2 * R2);
}

// ---------------------------------------------------------------------------
// Fused: featbf = bf16(feat) zero-padded + colsum0 = sum(feat, 0).
// 250 blocks x 192 threads; thread owns one column for 200 rows.
__global__ void feat_pass(const float* __restrict__ feat, bf16* __restrict__ featbf,
                          float* __restrict__ colsum0)
{
    int c  = threadIdx.x;           // 0..191
    int r0 = blockIdx.x * 200;
    const bool live = (c < IN_DIM);
    float acc = 0.0f;
    for (int i = 0; i < 200; ++i) {
        int r = r0 + i;
        if (r >= N_NODES) break;
        float v = live ? feat[(size_t)r * IN_DIM + c] : 0.0f;
        acc += v;
        featbf[(size_t)r * KPAD1 + c] = (bf16)v;
    }
    if (live) atomicAdd(&colsum0[c], acc);
}

// ---------------------------------------------------------------------------
// CSR build.
__global__ void degree_hist(const int* __restrict__ dst, int* __restrict__ deg)
{
    int e = blockIdx.x * blockDim.x + threadIdx.x;
    atomicAdd(&deg[dst[e]], 1);
}

__global__ void block_degsum(const int* __restrict__ deg, int* __restrict__ bsum)
{
    __shared__ int s[256];
    int t = threadIdx.x;
    int idx = blockIdx.x * 256 + t;
    int v = (idx < N_NODES) ? deg[idx] : 0;
    s[t] = v;
    __syncthreads();
    for (int off = 128; off > 0; off >>= 1) {
        if (t < off) s[t] += s[t + off];
        __syncthreads();
    }
    if (t == 0) bsum[blockIdx.x] = s[0];
}

__global__ void scan_bsum(const int* __restrict__ bsum, int* __restrict__ gsum)
{
    __shared__ int s[256];
    int t = threadIdx.x;
    int v = (t < NB) ? bsum[t] : 0;
    s[t] = v;
    __syncthreads();
    for (int off = 1; off < 256; off <<= 1) {
        int u = (t >= off) ? s[t - off] : 0;
        __syncthreads();
        s[t] += u;
        __syncthreads();
    }
    gsum[t] = s[t] - v;
}

__global__ void block_scan_write(const int* __restrict__ deg, const int* __restrict__ gsum,
                                 int* __restrict__ rowptr, int* __restrict__ cursor)
{
    __shared__ int s[256];
    int t = threadIdx.x;
    int idx = blockIdx.x * 256 + t;
    int v = (idx < N_NODES) ? deg[idx] : 0;
    s[t] = v;
    __syncthreads();
    for (int off = 1; off < 256; off <<= 1) {
        int u = (t >= off) ? s[t - off] : 0;
        __syncthreads();
        s[t] += u;
        __syncthreads();
    }
    int excl = s[t] - v + gsum[blockIdx.x];
    if (idx < N_NODES) {
        rowptr[idx] = excl;
        cursor[idx] = excl;
    }
    if (idx == 0) rowptr[N_NODES] = N_EDGES;
}

__global__ void csr_fill(const int* __restrict__ src, const int* __restrict__ dst,
                         int* __restrict__ cursor, int* __restrict__ csr_src)
{
    int e = blockIdx.x * blockDim.x + threadIdx.x;
    int p = atomicAdd(&cursor[dst[e]], 1);
    csr_src[p] = src[e];
}

// ---------------------------------------------------------------------------
// Gather layer 1 (bf16): xsum[n][:] = bf16( featbf[n][:] + sum featbf[src][:] )
// One wave per node, lanes 0..47 own 4 cols (8B); 4-src unroll for MLP.
__global__ void gather1(const bf16* __restrict__ featbf,
                        const int* __restrict__ rowptr,
                        const int* __restrict__ csr_src,
                        bf16* __restrict__ xsum)
{
    int wave = threadIdx.x >> 6;
    int lane = threadIdx.x & 63;
    int n = blockIdx.x * 4 + wave;
    if (n >= N_NODES || lane >= KPAD1 / 4) return;

    const int c = lane * 4;
    f32x4 acc;
    bf16x4 t0 = *(const bf16x4*)(featbf + (size_t)n * KPAD1 + c);
#pragma unroll
    for (int j = 0; j < 4; ++j) acc[j] = (float)t0[j];

    int jb = rowptr[n], je = rowptr[n + 1];
    for (; jb + 3 < je; jb += 4) {
        int s0 = csr_src[jb], s1 = csr_src[jb + 1];
        int s2 = csr_src[jb + 2], s3 = csr_src[jb + 3];
        bf16x4 u0 = *(const bf16x4*)(featbf + (size_t)s0 * KPAD1 + c);
        bf16x4 u1 = *(const bf16x4*)(featbf + (size_t)s1 * KPAD1 + c);
        bf16x4 u2 = *(const bf16x4*)(featbf + (size_t)s2 * KPAD1 + c);
        bf16x4 u3 = *(const bf16x4*)(featbf + (size_t)s3 * KPAD1 + c);
#pragma unroll
        for (int j = 0; j < 4; ++j)
            acc[j] += ((float)u0[j] + (float)u1[j]) + ((float)u2[j] + (float)u3[j]);
    }
    for (; jb < je; ++jb) {
        bf16x4 u0 = *(const bf16x4*)(featbf + (size_t)csr_src[jb] * KPAD1 + c);
#pragma unroll
        for (int j = 0; j < 4; ++j) acc[j] += (float)u0[j];
    }
    bf16x4 o;
#pragma unroll
    for (int j = 0; j < 4; ++j) o[j] = (bf16)acc[j];
    *(bf16x4*)(xsum + (size_t)n * KPAD1 + c) = o;
}

// ---------------------------------------------------------------------------
// Gather layer 2: y2[n][:] = bf16( node1[n][:] + sum node1[src][:] )
// One wave per node; half-wave h handles srcs j = jb+h, jb+h+2, ... with
// 16B/lane loads (32 lanes x bf16x8 = 512B row); 2x unroll = 4 rows in
// flight; final cross-half reduce via shfl_xor(32).
__global__ void gather2(const bf16* __restrict__ node1,
                        const int* __restrict__ rowptr,
                        const int* __restrict__ csr_src,
                        bf16* __restrict__ y2)
{
    int wave = threadIdx.x >> 6;
    int lane = threadIdx.x & 63;
    int n = blockIdx.x * 4 + wave;
    if (n >= N_NODES) return;
    const int h  = lane >> 5;
    const int c  = (lane & 31) * 8;

    f32x8 acc;
    if (h == 0) {
        bf16x8 t0 = *(const bf16x8*)(node1 + (size_t)n * HID + c);
#pragma unroll
        for (int j = 0; j < 8; ++j) acc[j] = (float)t0[j];
    } else {
#pragma unroll
        for (int j = 0; j < 8; ++j) acc[j] = 0.0f;
    }

    int je = rowptr[n + 1];
    int jj = rowptr[n] + h;
    for (; jj + 2 < je; jj += 4) {
        int s0 = csr_src[jj], s1 = csr_src[jj + 2];
        bf16x8 u0 = *(const bf16x8*)(node1 + (size_t)s0 * HID + c);
        bf16x8 u1 = *(const bf16x8*)(node1 + (size_t)s1 * HID + c);
#pragma unroll
        for (int j = 0; j < 8; ++j) acc[j] += (float)u0[j] + (float)u1[j];
    }
    if (jj < je) {
        bf16x8 u0 = *(const bf16x8*)(node1 + (size_t)csr_src[jj] * HID + c);
#pragma unroll
        for (int j = 0; j < 8; ++j) acc[j] += (float)u0[j];
    }

#pragma unroll
    for (int j = 0; j < 8; ++j) acc[j] += __shfl_xor(acc[j], 32, 64);

    if (h == 0) {
        bf16x8 o;
#pragma unroll
        for (int j = 0; j < 8; ++j) o[j] = (bf16)acc[j];
        *(bf16x8*)(y2 + (size_t)n * HID + c) = o;
    }
}

// ---------------------------------------------------------------------------
// GEMM v2 (+ optional fused column-sum of the post-relu output).
// Block = 4 waves, tile 128 rows x 256 cols; wave w owns rows [w*32,w*32+32)
// x 256 cols = 8 x mfma_f32_32x32x16_bf16. Wt k-slice staged frag-major in
// LDS via global_load_lds width=16 (conflict-free ds_read_b128).
// A/B frag: row/col = lane&31, k = (lane>>5)*8 + j
// C/D     : col = lane&31, row = (reg&3) + 8*(reg>>2) + 4*(lane>>5)
template<int KPAD>
__launch_bounds__(256)
__global__ void gemm_relu2(const bf16* __restrict__ X,
                           const bf16* __restrict__ Wt,
                           const float* __restrict__ bias,
                           bf16* __restrict__ out_bf,
                           float* __restrict__ colsum,   // nullable
                           int M)
{
    __shared__ __align__(128) bf16 sB[8192];   // 16 KB
    __shared__ float cs[256];

    const int tid  = threadIdx.x;
    const int w    = tid >> 6;
    const int lane = tid & 63;
    const int p    = lane >> 5;
    const int cn   = lane & 31;
    const int m_base = blockIdx.x * 128 + w * 32;

    int arow = m_base + cn;
    if (arow >= M) arow = M - 1;   // clamp (stores guarded)

    f32x16 acc[8];
#pragma unroll
    for (int j = 0; j < 8; ++j)
#pragma unroll
        for (int r = 0; r < 16; ++r) acc[j][r] = 0.0f;

    for (int k0 = 0; k0 < KPAD; k0 += 32) {
        __syncthreads();
#pragma unroll
        for (int i = 0; i < 4; ++i) {
            int fb = w * 4 + i;
            int j  = fb >> 1;
            int kk = fb & 1;
            const bf16* g = Wt + (size_t)(j * 32 + cn) * KPAD + k0 + kk * 16 + p * 8;
            GLDS16(g, sB + fb * 512);
        }
        __syncthreads();

#pragma unroll
        for (int kk = 0; kk < 2; ++kk) {
            bf16x8 a = *(const bf16x8*)(X + (size_t)arow * KPAD + k0 + kk * 16 + p * 8);
#pragma unroll
            for (int j = 0; j < 8; ++j) {
                bf16x8 b = *(const bf16x8*)(sB + (j * 2 + kk) * 512 + lane * 8);
                acc[j] = __builtin_amdgcn_mfma_f32_32x32x16_bf16(a, b, acc[j], 0, 0, 0);
            }
        }
    }

    if (colsum) {
        cs[tid] = 0.0f;
        __syncthreads();
    }

#pragma unroll
    for (int j = 0; j < 8; ++j) {
        const int col = j * 32 + cn;
        const float bv = bias[col];
        float part = 0.0f;
#pragma unroll
        for (int r = 0; r < 16; ++r) {
            int rl = (r & 3) + 8 * (r >> 2) + 4 * p;
            int mo = m_base + rl;
            if (mo < M) {
                float v = acc[j][r] + bv;
                v = v > 0.0f ? v : 0.0f;
                out_bf[(size_t)mo * HID + col] = (bf16)v;
                part += v;
            }
        }
        if (colsum) {
            part += __shfl_xor(part, 32, 64);   // combine the two p-halves
            if (p == 0) atomicAdd(&cs[col], part);
        }
    }

    if (colsum) {
        __syncthreads();
        atomicAdd(&colsum[tid], cs[tid]);
    }
}

// ---------------------------------------------------------------------------
// Graph head: three GEMVs + sum + final GEMV, single block of 256 threads.
__global__ void graph_head(const float* __restrict__ cs0,
                           const float* __restrict__ cs1,
                           const float* __restrict__ cs2,
                           const float* __restrict__ g0w, const float* __restrict__ g0b,
                           const float* __restrict__ g1w, const float* __restrict__ g1b,
                           const float* __restrict__ g2w, const float* __restrict__ g2b,
                           const float* __restrict__ glw, const float* __restrict__ glb,
                           float* __restrict__ gvec)
{
    __shared__ float v0[IN_DIM], v1[HID], v2[HID], gs[HID];
    int t = threadIdx.x;
    if (t < IN_DIM) v0[t] = cs0[t];
    v1[t] = cs1[t];
    v2[t] = cs2[t];
    __syncthreads();

    float a0 = 0.0f, a1 = 0.0f, a2 = 0.0f;
    for (int k = 0; k < IN_DIM; ++k) a0 += v0[k] * g0w[k * HID + t];
    for (int k = 0; k < HID; ++k) {
        a1 += v1[k] * g1w[k * HID + t];
        a2 += v2[k] * g2w[k * HID + t];
    }
    float e0 = fmaxf(a0 + g0b[t], 0.0f);
    float e1 = fmaxf(a1 + g1b[t], 0.0f);
    float e2 = fmaxf(a2 + g2b[t], 0.0f);
    gs[t] = e0 + e1 + e2;
    __syncthreads();

    float a3 = 0.0f;
    for (int k = 0; k < HID; ++k) a3 += gs[k] * glw[k * HID + t];
    gvec[t] = fmaxf(a3 + glb[t], 0.0f);
}

// ---------------------------------------------------------------------------
// out[n,c] = node2[n,c](bf16) + gvec[c] (f32 out); 4 elements per thread.
__global__ void final_add(const bf16* __restrict__ node2,
                          const float* __restrict__ gvec,
                          float* __restrict__ out)
{
    int idx = blockIdx.x * blockDim.x + threadIdx.x;
    size_t base = (size_t)idx * 4;
    int c = (int)(base & (HID - 1));
    bf16x4 v = *(const bf16x4*)(node2 + base);
    f32x4 g = *(const f32x4*)(gvec + c);
    f32x4 o;
#pragma unroll
    for (int j = 0; j < 4; ++j) o[j] = (float)v[j] + g[j];
    *(f32x4*)(out + base) = o;
}

// ---------------------------------------------------------------------------
extern "C" void kernel_launch(void* const* d_in, const int* in_sizes, int n_in,
                              void* d_out, int out_size, void* d_ws, size_t ws_size,
                              hipStream_t stream)
{
    const float* feat = (const float*)d_in[0];
    const int*   ei   = (const int*)d_in[1];
    const int*   src  = ei;
    const int*   dst  = ei + N_EDGES;
    const float* g0w = (const float*)d_in[2],  *g0b = (const float*)d_in[3];
    const float* g1w = (const float*)d_in[4],  *g1b = (const float*)d_in[5];
    const float* g2w = (const float*)d_in[6],  *g2b = (const float*)d_in[7];
    const float* glw = (const float*)d_in[8],  *glb = (const float*)d_in[9];
    const float* m1aw = (const float*)d_in[10], *m1ab = (const float*)d_in[11];
    const float* m1bw = (const float*)d_in[12], *m1bb = (const float*)d_in[13];
    const float* m2aw = (const float*)d_in[14], *m2ab = (const float*)d_in[15];
    const float* m2bw = (const float*)d_in[16], *m2bb = (const float*)d_in[17];
    float* out = (float*)d_out;

    char* ws = (char*)d_ws;
    size_t off = 0;
    auto alloc = [&](size_t bytes) -> void* {
        void* p = ws + off;
        off += (bytes + 255) & ~(size_t)255;
        return p;
    };
    bf16*  featbf = (bf16*)alloc((size_t)N_NODES * KPAD1 * 2);
    bf16*  xsum  = (bf16*) alloc((size_t)N_NODES * KPAD1 * 2);
    bf16*  y2    = (bf16*) alloc((size_t)N_NODES * HID * 2);
    bf16*  node2 = (bf16*) alloc((size_t)N_NODES * HID * 2);
    bf16*  h1    = (bf16*) alloc((size_t)N_NODES * HID * 2);   // reused as h2
    bf16*  node1 = (bf16*) alloc((size_t)N_NODES * HID * 2);
    bf16*  Wt1   = (bf16*) alloc((size_t)HID * KPAD1 * 2);
    bf16*  Wt2   = (bf16*) alloc((size_t)HID * HID * 2);
    bf16*  Wt3   = (bf16*) alloc((size_t)HID * HID * 2);
    bf16*  Wt4   = (bf16*) alloc((size_t)HID * HID * 2);
    int*   deg     = (int*)alloc((size_t)N_NODES * 4);
    int*   rowptr  = (int*)alloc((size_t)(N_NODES + 1) * 4);
    int*   cursor  = (int*)alloc((size_t)N_NODES * 4);
    int*   csr_src = (int*)alloc((size_t)N_EDGES * 4);
    int*   bsum    = (int*)alloc(256 * 4);
    int*   gsum    = (int*)alloc(256 * 4);
    float* csums = (float*)alloc((192 + 256 + 256 + 256) * 4);
    float* colsum0 = csums;            // 192 (162 used)
    float* colsum1 = csums + 192;      // 256
    float* colsum2 = csums + 448;      // 256
    float* gvec    = csums + 704;      // 256

    hipMemsetAsync(csums, 0, 704 * 4, stream);
    hipMemsetAsync(deg, 0, (size_t)N_NODES * 4, stream);

    // all 4 weight transposes, one launch (245760 elems)
    wt_transpose_all<<<(HID * KPAD1 + 3 * HID * HID + 255) / 256, 256, 0, stream>>>(
        m1aw, m1bw, m2aw, m2bw, Wt1, Wt2, Wt3, Wt4);

    // fused feat -> bf16 + colsum0
    feat_pass<<<250, 192, 0, stream>>>(feat, featbf, colsum0);

    // CSR build (grouped by dst)
    degree_hist<<<N_EDGES / 256, 256, 0, stream>>>(dst, deg);
    block_degsum<<<NB, 256, 0, stream>>>(deg, bsum);
    scan_bsum<<<1, 256, 0, stream>>>(bsum, gsum);
    block_scan_write<<<NB, 256, 0, stream>>>(deg, gsum, rowptr, cursor);
    csr_fill<<<N_EDGES / 256, 256, 0, stream>>>(src, dst, cursor, csr_src);

    // xsum = bf16(feat + gather(feat))
    gather1<<<(N_NODES + 3) / 4, 256, 0, stream>>>(featbf, rowptr, csr_src, xsum);

    const int gblocks = (N_NODES + 127) / 128;
    // h1 = relu(xsum @ m1a_w + b)
    gemm_relu2<KPAD1><<<gblocks, 256, 0, stream>>>(xsum, Wt1, m1ab, h1, nullptr, N_NODES);
    // node1 = relu(h1 @ m1b_w + b), colsum1 fused
    gemm_relu2<HID><<<gblocks, 256, 0, stream>>>(h1, Wt2, m1bb, node1, colsum1, N_NODES);
    // y2 = bf16(node1 + gather(node1))
    gather2<<<(N_NODES + 3) / 4, 256, 0, stream>>>(node1, rowptr, csr_src, y2);
    // h2 = relu(y2 @ m2a_w + b)  (reuse h1 buffer)
    gemm_relu2<HID><<<gblocks, 256, 0, stream>>>(y2, Wt3, m2ab, h1, nullptr, N_NODES);
    // node2 = relu(h2 @ m2b_w + b), colsum2 fused
    gemm_relu2<HID><<<gblocks, 256, 0, stream>>>(h1, Wt4, m2bb, node2, colsum2, N_NODES);
    // graph head -> gvec = g_last
    graph_head<<<1, 256, 0, stream>>>(colsum0, colsum1, colsum2,
                                      g0w, g0b, g1w, g1b, g2w, g2b, glw, glb, gvec);
    // out = node2 + gvec
    final_add<<<((size_t)N_NODES * HID / 4 + 255) / 256, 256, 0, stream>>>(node2, gvec, out);
    (void)in_sizes; (void)n_in; (void)out_size; (void)ws_size;
}

// Round 7
// 535.446 us; speedup vs baseline: 4.8303x; 1.1152x over previous
//
#include <hip/hip_runtime.h>

#define N_NODES 50000
#define N_EDGES 800000
#define IN_DIM  162
#define HID     256
#define KPAD1   192   // IN_DIM padded to multiple of 32
#define NB      ((N_NODES + 255) / 256)   // 196 scan blocks

typedef __bf16 bf16;
typedef __bf16 bf16x8 __attribute__((ext_vector_type(8)));
typedef __bf16 bf16x4 __attribute__((ext_vector_type(4)));
typedef float  f32x4  __attribute__((ext_vector_type(4)));
typedef float  f32x8  __attribute__((ext_vector_type(8)));
typedef float  f32x16 __attribute__((ext_vector_type(16)));

#define GLDS16(g, l) __builtin_amdgcn_global_load_lds( \
    (const __attribute__((address_space(1))) void*)(g), \
    (__attribute__((address_space(3))) void*)(l), 16, 0, 0)

// ---------------------------------------------------------------------------
// All 4 weight transposes in one launch. W[K][HID] f32 -> Wt[HID][KPAD] bf16.
__device__ __forceinline__ void wt_one(const float* W, bf16* Wt, int K, int KPAD, int idx)
{
    int n = idx / KPAD;
    int k = idx - n * KPAD;
    Wt[idx] = (k < K) ? (bf16)W[(size_t)k * HID + n] : (bf16)0.0f;
}

__global__ void wt_transpose_all(const float* __restrict__ m1aw, const float* __restrict__ m1bw,
                                 const float* __restrict__ m2aw, const float* __restrict__ m2bw,
                                 bf16* __restrict__ Wt1, bf16* __restrict__ Wt2,
                                 bf16* __restrict__ Wt3, bf16* __restrict__ Wt4)
{
    const int R1 = HID * KPAD1;
    const int R2 = HID * HID;
    int idx = blockIdx.x * blockDim.x + threadIdx.x;
    if (idx < R1)                 wt_one(m1aw, Wt1, IN_DIM, KPAD1, idx);
    else if (idx < R1 + R2)       wt_one(m1bw, Wt2, HID, HID, idx - R1);
    else if (idx < R1 + 2 * R2)   wt_one(m2aw, Wt3, HID, HID, idx - R1 - R2);
    else if (idx < R1 + 3 * R2)   wt_one(m2bw, Wt4, HID, HID, idx - R1 - 2 * R2);
}

// ---------------------------------------------------------------------------
// feat f32 [N, IN_DIM] -> featbf bf16 [N, KPAD1] (cols >= IN_DIM zeroed).
// Wide grid, 4 cols/thread.
__global__ void feat_to_bf16(const float* __restrict__ feat, bf16* __restrict__ featbf)
{
    int idx = blockIdx.x * blockDim.x + threadIdx.x;  // over N*KPAD1/4
    int r = idx / (KPAD1 / 4);
    int c4 = (idx - r * (KPAD1 / 4)) * 4;
    if (r >= N_NODES) return;
    bf16x4 o;
#pragma unroll
    for (int j = 0; j < 4; ++j) {
        int c = c4 + j;
        o[j] = (c < IN_DIM) ? (bf16)feat[(size_t)r * IN_DIM + c] : (bf16)0.0f;
    }
    *(bf16x4*)(featbf + (size_t)r * KPAD1 + c4) = o;
}

// ---------------------------------------------------------------------------
// colsum8[b&7][c] += partial column sums of feat; 1000 blocks x 192 thr,
// 50 rows/block; 8-slot spread keeps per-address serialization at ~125.
__global__ void colsum_feat8(const float* __restrict__ feat, float* __restrict__ colsum8)
{
    int c  = threadIdx.x;
    int r0 = blockIdx.x * 50;
    if (c >= IN_DIM) return;
    float acc = 0.0f;
#pragma unroll 2
    for (int i = 0; i < 50; ++i) {
        int r = r0 + i;
        if (r < N_NODES) acc += feat[(size_t)r * IN_DIM + c];
    }
    atomicAdd(&colsum8[(blockIdx.x & 7) * KPAD1 + c], acc);
}

// ---------------------------------------------------------------------------
// CSR build.
__global__ void degree_hist(const int* __restrict__ dst, int* __restrict__ deg)
{
    int e = blockIdx.x * blockDim.x + threadIdx.x;
    atomicAdd(&deg[dst[e]], 1);
}

__global__ void block_degsum(const int* __restrict__ deg, int* __restrict__ bsum)
{
    __shared__ int s[256];
    int t = threadIdx.x;
    int idx = blockIdx.x * 256 + t;
    int v = (idx < N_NODES) ? deg[idx] : 0;
    s[t] = v;
    __syncthreads();
    for (int off = 128; off > 0; off >>= 1) {
        if (t < off) s[t] += s[t + off];
        __syncthreads();
    }
    if (t == 0) bsum[blockIdx.x] = s[0];
}

__global__ void scan_bsum(const int* __restrict__ bsum, int* __restrict__ gsum)
{
    __shared__ int s[256];
    int t = threadIdx.x;
    int v = (t < NB) ? bsum[t] : 0;
    s[t] = v;
    __syncthreads();
    for (int off = 1; off < 256; off <<= 1) {
        int u = (t >= off) ? s[t - off] : 0;
        __syncthreads();
        s[t] += u;
        __syncthreads();
    }
    gsum[t] = s[t] - v;
}

__global__ void block_scan_write(const int* __restrict__ deg, const int* __restrict__ gsum,
                                 int* __restrict__ rowptr, int* __restrict__ cursor)
{
    __shared__ int s[256];
    int t = threadIdx.x;
    int idx = blockIdx.x * 256 + t;
    int v = (idx < N_NODES) ? deg[idx] : 0;
    s[t] = v;
    __syncthreads();
    for (int off = 1; off < 256; off <<= 1) {
        int u = (t >= off) ? s[t - off] : 0;
        __syncthreads();
        s[t] += u;
        __syncthreads();
    }
    int excl = s[t] - v + gsum[blockIdx.x];
    if (idx < N_NODES) {
        rowptr[idx] = excl;
        cursor[idx] = excl;
    }
    if (idx == 0) rowptr[N_NODES] = N_EDGES;
}

__global__ void csr_fill(const int* __restrict__ src, const int* __restrict__ dst,
                         int* __restrict__ cursor, int* __restrict__ csr_src)
{
    int e = blockIdx.x * blockDim.x + threadIdx.x;
    int p = atomicAdd(&cursor[dst[e]], 1);
    csr_src[p] = src[e];
}

// ---------------------------------------------------------------------------
// Gather layer 1: xsum[n][:] = bf16( featbf[n][:] + sum featbf[src][:] )
// One wave per node. Half-wave h fetches src rows j = jb+h, jb+h+2, ...;
// lane owns 16B (bf16x8); row = 384B = 24 active lanes per half.
// One load instruction covers TWO src rows (one per half). shfl_xor(32) reduce.
__global__ void gather1(const bf16* __restrict__ featbf,
                        const int* __restrict__ rowptr,
                        const int* __restrict__ csr_src,
                        bf16* __restrict__ xsum)
{
    int wave = threadIdx.x >> 6;
    int lane = threadIdx.x & 63;
    int n = blockIdx.x * 4 + wave;
    if (n >= N_NODES) return;
    const int h   = lane >> 5;
    const int cl  = lane & 31;
    const int c   = cl * 8;            // element offset; valid when cl < 24
    const bool act = (cl < 24);        // 24*8 = 192

    f32x8 acc;
#pragma unroll
    for (int j = 0; j < 8; ++j) acc[j] = 0.0f;
    if (act && h == 0) {
        bf16x8 t0 = *(const bf16x8*)(featbf + (size_t)n * KPAD1 + c);
#pragma unroll
        for (int j = 0; j < 8; ++j) acc[j] = (float)t0[j];
    }

    int je = rowptr[n + 1];
    int jj = rowptr[n] + h;
    for (; jj + 6 < je; jj += 8) {
        int s0 = csr_src[jj], s1 = csr_src[jj + 2];
        int s2 = csr_src[jj + 4], s3 = csr_src[jj + 6];
        if (act) {
            bf16x8 u0 = *(const bf16x8*)(featbf + (size_t)s0 * KPAD1 + c);
            bf16x8 u1 = *(const bf16x8*)(featbf + (size_t)s1 * KPAD1 + c);
            bf16x8 u2 = *(const bf16x8*)(featbf + (size_t)s2 * KPAD1 + c);
            bf16x8 u3 = *(const bf16x8*)(featbf + (size_t)s3 * KPAD1 + c);
#pragma unroll
            for (int j = 0; j < 8; ++j)
                acc[j] += ((float)u0[j] + (float)u1[j]) + ((float)u2[j] + (float)u3[j]);
        }
    }
    for (; jj < je; jj += 2) {
        int s0 = csr_src[jj];
        if (act) {
            bf16x8 u0 = *(const bf16x8*)(featbf + (size_t)s0 * KPAD1 + c);
#pragma unroll
            for (int j = 0; j < 8; ++j) acc[j] += (float)u0[j];
        }
    }

#pragma unroll
    for (int j = 0; j < 8; ++j) acc[j] += __shfl_xor(acc[j], 32, 64);

    if (act && h == 0) {
        bf16x8 o;
#pragma unroll
        for (int j = 0; j < 8; ++j) o[j] = (bf16)acc[j];
        *(bf16x8*)(xsum + (size_t)n * KPAD1 + c) = o;
    }
}

// ---------------------------------------------------------------------------
// Gather layer 2: y2[n][:] = bf16( node1[n][:] + sum node1[src][:] )
// Half-wave per src row, 16B/lane (32 lanes x bf16x8 = 512B row), 4-row
// unroll per half (8 rows/wave in flight); shfl_xor(32) reduce.
__global__ void gather2(const bf16* __restrict__ node1,
                        const int* __restrict__ rowptr,
                        const int* __restrict__ csr_src,
                        bf16* __restrict__ y2)
{
    int wave = threadIdx.x >> 6;
    int lane = threadIdx.x & 63;
    int n = blockIdx.x * 4 + wave;
    if (n >= N_NODES) return;
    const int h  = lane >> 5;
    const int c  = (lane & 31) * 8;

    f32x8 acc;
    if (h == 0) {
        bf16x8 t0 = *(const bf16x8*)(node1 + (size_t)n * HID + c);
#pragma unroll
        for (int j = 0; j < 8; ++j) acc[j] = (float)t0[j];
    } else {
#pragma unroll
        for (int j = 0; j < 8; ++j) acc[j] = 0.0f;
    }

    int je = rowptr[n + 1];
    int jj = rowptr[n] + h;
    for (; jj + 6 < je; jj += 8) {
        int s0 = csr_src[jj], s1 = csr_src[jj + 2];
        int s2 = csr_src[jj + 4], s3 = csr_src[jj + 6];
        bf16x8 u0 = *(const bf16x8*)(node1 + (size_t)s0 * HID + c);
        bf16x8 u1 = *(const bf16x8*)(node1 + (size_t)s1 * HID + c);
        bf16x8 u2 = *(const bf16x8*)(node1 + (size_t)s2 * HID + c);
        bf16x8 u3 = *(const bf16x8*)(node1 + (size_t)s3 * HID + c);
#pragma unroll
        for (int j = 0; j < 8; ++j)
            acc[j] += ((float)u0[j] + (float)u1[j]) + ((float)u2[j] + (float)u3[j]);
    }
    for (; jj < je; jj += 2) {
        bf16x8 u0 = *(const bf16x8*)(node1 + (size_t)csr_src[jj] * HID + c);
#pragma unroll
        for (int j = 0; j < 8; ++j) acc[j] += (float)u0[j];
    }

#pragma unroll
    for (int j = 0; j < 8; ++j) acc[j] += __shfl_xor(acc[j], 32, 64);

    if (h == 0) {
        bf16x8 o;
#pragma unroll
        for (int j = 0; j < 8; ++j) o[j] = (bf16)acc[j];
        *(bf16x8*)(y2 + (size_t)n * HID + c) = o;
    }
}

// ---------------------------------------------------------------------------
// GEMM v2 (+ optional fused column-sum of the post-relu output).
// Block = 4 waves, tile 128 rows x 256 cols; wave w owns rows [w*32,w*32+32)
// x 256 cols = 8 x mfma_f32_32x32x16_bf16. Wt k-slice staged frag-major in
// LDS via global_load_lds width=16 (conflict-free ds_read_b128).
// A/B frag: row/col = lane&31, k = (lane>>5)*8 + j
// C/D     : col = lane&31, row = (reg&3) + 8*(reg>>2) + 4*(lane>>5)
template<int KPAD>
__launch_bounds__(256)
__global__ void gemm_relu2(const bf16* __restrict__ X,
                           const bf16* __restrict__ Wt,
                           const float* __restrict__ bias,
                           bf16* __restrict__ out_bf,
                           float* __restrict__ colsum,   // nullable
                           int M)
{
    __shared__ __align__(128) bf16 sB[8192];   // 16 KB
    __shared__ float cs[256];

    const int tid  = threadIdx.x;
    const int w    = tid >> 6;
    const int lane = tid & 63;
    const int p    = lane >> 5;
    const int cn   = lane & 31;
    const int m_base = blockIdx.x * 128 + w * 32;

    int arow = m_base + cn;
    if (arow >= M) arow = M - 1;   // clamp (stores guarded)

    f32x16 acc[8];
#pragma unroll
    for (int j = 0; j < 8; ++j)
#pragma unroll
        for (int r = 0; r < 16; ++r) acc[j][r] = 0.0f;

    for (int k0 = 0; k0 < KPAD; k0 += 32) {
        __syncthreads();
#pragma unroll
        for (int i = 0; i < 4; ++i) {
            int fb = w * 4 + i;
            int j  = fb >> 1;
            int kk = fb & 1;
            const bf16* g = Wt + (size_t)(j * 32 + cn) * KPAD + k0 + kk * 16 + p * 8;
            GLDS16(g, sB + fb * 512);
        }
        __syncthreads();

#pragma unroll
        for (int kk = 0; kk < 2; ++kk) {
            bf16x8 a = *(const bf16x8*)(X + (size_t)arow * KPAD + k0 + kk * 16 + p * 8);
#pragma unroll
            for (int j = 0; j < 8; ++j) {
                bf16x8 b = *(const bf16x8*)(sB + (j * 2 + kk) * 512 + lane * 8);
                acc[j] = __builtin_amdgcn_mfma_f32_32x32x16_bf16(a, b, acc[j], 0, 0, 0);
            }
        }
    }

    if (colsum) {
        cs[tid] = 0.0f;
        __syncthreads();
    }

#pragma unroll
    for (int j = 0; j < 8; ++j) {
        const int col = j * 32 + cn;
        const float bv = bias[col];
        float part = 0.0f;
#pragma unroll
        for (int r = 0; r < 16; ++r) {
            int rl = (r & 3) + 8 * (r >> 2) + 4 * p;
            int mo = m_base + rl;
            if (mo < M) {
                float v = acc[j][r] + bv;
                v = v > 0.0f ? v : 0.0f;
                out_bf[(size_t)mo * HID + col] = (bf16)v;
                part += v;
            }
        }
        if (colsum) {
            part += __shfl_xor(part, 32, 64);   // combine the two p-halves
            if (p == 0) atomicAdd(&cs[col], part);
        }
    }

    if (colsum) {
        __syncthreads();
        atomicAdd(&colsum[tid], cs[tid]);
    }
}

// ---------------------------------------------------------------------------
// Graph head: three GEMVs + sum + final GEMV, single block of 256 threads.
// cs0_8 is 8 x KPAD1 partial slots.
__global__ void graph_head(const float* __restrict__ cs0_8,
                           const float* __restrict__ cs1,
                           const float* __restrict__ cs2,
                           const float* __restrict__ g0w, const float* __restrict__ g0b,
                           const float* __restrict__ g1w, const float* __restrict__ g1b,
                           const float* __restrict__ g2w, const float* __restrict__ g2b,
                           const float* __restrict__ glw, const float* __restrict__ glb,
                           float* __restrict__ gvec)
{
    __shared__ float v0[IN_DIM], v1[HID], v2[HID], gs[HID];
    int t = threadIdx.x;
    if (t < IN_DIM) {
        float s = 0.0f;
#pragma unroll
        for (int i = 0; i < 8; ++i) s += cs0_8[i * KPAD1 + t];
        v0[t] = s;
    }
    v1[t] = cs1[t];
    v2[t] = cs2[t];
    __syncthreads();

    float a0 = 0.0f, a1 = 0.0f, a2 = 0.0f;
    for (int k = 0; k < IN_DIM; ++k) a0 += v0[k] * g0w[k * HID + t];
    for (int k = 0; k < HID; ++k) {
        a1 += v1[k] * g1w[k * HID + t];
        a2 += v2[k] * g2w[k * HID + t];
    }
    float e0 = fmaxf(a0 + g0b[t], 0.0f);
    float e1 = fmaxf(a1 + g1b[t], 0.0f);
    float e2 = fmaxf(a2 + g2b[t], 0.0f);
    gs[t] = e0 + e1 + e2;
    __syncthreads();

    float a3 = 0.0f;
    for (int k = 0; k < HID; ++k) a3 += gs[k] * glw[k * HID + t];
    gvec[t] = fmaxf(a3 + glb[t], 0.0f);
}

// ---------------------------------------------------------------------------
// out[n,c] = node2[n,c](bf16) + gvec[c] (f32 out); 4 elements per thread.
__global__ void final_add(const bf16* __restrict__ node2,
                          const float* __restrict__ gvec,
                          float* __restrict__ out)
{
    int idx = blockIdx.x * blockDim.x + threadIdx.x;
    size_t base = (size_t)idx * 4;
    int c = (int)(base & (HID - 1));
    bf16x4 v = *(const bf16x4*)(node2 + base);
    f32x4 g = *(const f32x4*)(gvec + c);
    f32x4 o;
#pragma unroll
    for (int j = 0; j < 4; ++j) o[j] = (float)v[j] + g[j];
    *(f32x4*)(out + base) = o;
}

// ---------------------------------------------------------------------------
extern "C" void kernel_launch(void* const* d_in, const int* in_sizes, int n_in,
                              void* d_out, int out_size, void* d_ws, size_t ws_size,
                              hipStream_t stream)
{
    const float* feat = (const float*)d_in[0];
    const int*   ei   = (const int*)d_in[1];
    const int*   src  = ei;
    const int*   dst  = ei + N_EDGES;
    const float* g0w = (const float*)d_in[2],  *g0b = (const float*)d_in[3];
    const float* g1w = (const float*)d_in[4],  *g1b = (const float*)d_in[5];
    const float* g2w = (const float*)d_in[6],  *g2b = (const float*)d_in[7];
    const float* glw = (const float*)d_in[8],  *glb = (const float*)d_in[9];
    const float* m1aw = (const float*)d_in[10], *m1ab = (const float*)d_in[11];
    const float* m1bw = (const float*)d_in[12], *m1bb = (const float*)d_in[13];
    const float* m2aw = (const float*)d_in[14], *m2ab = (const float*)d_in[15];
    const float* m2bw = (const float*)d_in[16], *m2bb = (const float*)d_in[17];
    float* out = (float*)d_out;

    char* ws = (char*)d_ws;
    size_t off = 0;
    auto alloc = [&](size_t bytes) -> void* {
        void* p = ws + off;
        off += (bytes + 255) & ~(size_t)255;
        return p;
    };
    bf16*  featbf = (bf16*)alloc((size_t)N_NODES * KPAD1 * 2);
    bf16*  xsum  = (bf16*) alloc((size_t)N_NODES * KPAD1 * 2);
    bf16*  y2    = (bf16*) alloc((size_t)N_NODES * HID * 2);
    bf16*  node2 = (bf16*) alloc((size_t)N_NODES * HID * 2);
    bf16*  h1    = (bf16*) alloc((size_t)N_NODES * HID * 2);   // reused as h2
    bf16*  node1 = (bf16*) alloc((size_t)N_NODES * HID * 2);
    bf16*  Wt1   = (bf16*) alloc((size_t)HID * KPAD1 * 2);
    bf16*  Wt2   = (bf16*) alloc((size_t)HID * HID * 2);
    bf16*  Wt3   = (bf16*) alloc((size_t)HID * HID * 2);
    bf16*  Wt4   = (bf16*) alloc((size_t)HID * HID * 2);
    int*   deg     = (int*)alloc((size_t)N_NODES * 4);
    int*   rowptr  = (int*)alloc((size_t)(N_NODES + 1) * 4);
    int*   cursor  = (int*)alloc((size_t)N_NODES * 4);
    int*   csr_src = (int*)alloc((size_t)N_EDGES * 4);
    int*   bsum    = (int*)alloc(256 * 4);
    int*   gsum    = (int*)alloc(256 * 4);
    float* csums   = (float*)alloc((8 * KPAD1 + 256 + 256 + 256) * 4);
    float* colsum0_8 = csums;                    // 8 x 192 partial slots
    float* colsum1   = csums + 8 * KPAD1;        // 256
    float* colsum2   = csums + 8 * KPAD1 + 256;  // 256
    float* gvec      = csums + 8 * KPAD1 + 512;  // 256

    hipMemsetAsync(csums, 0, (8 * KPAD1 + 512) * 4, stream);
    hipMemsetAsync(deg, 0, (size_t)N_NODES * 4, stream);

    // all 4 weight transposes, one launch
    wt_transpose_all<<<(HID * KPAD1 + 3 * HID * HID + 255) / 256, 256, 0, stream>>>(
        m1aw, m1bw, m2aw, m2bw, Wt1, Wt2, Wt3, Wt4);

    // feat -> bf16 (wide vectorized grid)
    feat_to_bf16<<<((size_t)N_NODES * (KPAD1 / 4) + 255) / 256, 256, 0, stream>>>(feat, featbf);
    // colsum0 partials (8-slot spread)
    colsum_feat8<<<1000, 192, 0, stream>>>(feat, colsum0_8);

    // CSR build (grouped by dst)
    degree_hist<<<N_EDGES / 256, 256, 0, stream>>>(dst, deg);
    block_degsum<<<NB, 256, 0, stream>>>(deg, bsum);
    scan_bsum<<<1, 256, 0, stream>>>(bsum, gsum);
    block_scan_write<<<NB, 256, 0, stream>>>(deg, gsum, rowptr, cursor);
    csr_fill<<<N_EDGES / 256, 256, 0, stream>>>(src, dst, cursor, csr_src);

    // xsum = bf16(feat + gather(feat))
    gather1<<<(N_NODES + 3) / 4, 256, 0, stream>>>(featbf, rowptr, csr_src, xsum);

    const int gblocks = (N_NODES + 127) / 128;
    // h1 = relu(xsum @ m1a_w + b)
    gemm_relu2<KPAD1><<<gblocks, 256, 0, stream>>>(xsum, Wt1, m1ab, h1, nullptr, N_NODES);
    // node1 = relu(h1 @ m1b_w + b), colsum1 fused
    gemm_relu2<HID><<<gblocks, 256, 0, stream>>>(h1, Wt2, m1bb, node1, colsum1, N_NODES);
    // y2 = bf16(node1 + gather(node1))
    gather2<<<(N_NODES + 3) / 4, 256, 0, stream>>>(node1, rowptr, csr_src, y2);
    // h2 = relu(y2 @ m2a_w + b)  (reuse h1 buffer)
    gemm_relu2<HID><<<gblocks, 256, 0, stream>>>(y2, Wt3, m2ab, h1, nullptr, N_NODES);
    // node2 = relu(h2 @ m2b_w + b), colsum2 fused
    gemm_relu2<HID><<<gblocks, 256, 0, stream>>>(h1, Wt4, m2bb, node2, colsum2, N_NODES);
    // graph head -> gvec = g_last
    graph_head<<<1, 256, 0, stream>>>(colsum0_8, colsum1, colsum2,
                                      g0w, g0b, g1w, g1b, g2w, g2b, glw, glb, gvec);
    // out = node2 + gvec
    final_add<<<((size_t)N_NODES * HID / 4 + 255) / 256, 256, 0, stream>>>(node2, gvec, out);
    (void)in_sizes; (void)n_in; (void)out_size; (void)ws_size;
}